// Round 2
// baseline (32904.425 us; speedup 1.0000x reference)
//
#include <hip/hip_runtime.h>
#include <hip/hip_bf16.h>
#include <cmath>

#define NL 8
#define BB 8
#define LL 2048
#define DM 512
#define DI 1024
#define DS 32
#define DR 32
#define NROWS (BB * LL)   // 16384

// ---------------------------------------------------------------------------
// RMSNorm: one block (256 thr) per row of 512. float2 per thread.
// ---------------------------------------------------------------------------
__global__ __launch_bounds__(256) void rmsnorm_kernel(
    const float* __restrict__ x, const float* __restrict__ w,
    float* __restrict__ out) {
  const int row = blockIdx.x;
  const int tid = threadIdx.x;
  const float2 v = reinterpret_cast<const float2*>(x + (size_t)row * DM)[tid];
  float ss = v.x * v.x + v.y * v.y;
#pragma unroll
  for (int off = 1; off < 64; off <<= 1) ss += __shfl_xor(ss, off, 64);
  __shared__ float smem[4];
  if ((tid & 63) == 0) smem[tid >> 6] = ss;
  __syncthreads();
  const float tot = smem[0] + smem[1] + smem[2] + smem[3];
  const float scale = rsqrtf(tot * (1.0f / DM) + 1e-5f);
  const float2 wv = reinterpret_cast<const float2*>(w)[tid];
  float2 o;
  o.x = v.x * scale * wv.x;
  o.y = v.y * scale * wv.y;
  reinterpret_cast<float2*>(out + (size_t)row * DM)[tid] = o;
}

// ---------------------------------------------------------------------------
// Tiled fp32 GEMM: C[M,N] = A[M,K] * B[N,K]^T  (both row-major).
// 64x64 tile, 256 threads, 4x4 per thread, K-tile 16.
// EPI 0: plain store; EPI 1: softplus(v + bias[n]); EPI 2: C += v.
// M must be a multiple of 64. N may be ragged (x_proj N=96).
// ---------------------------------------------------------------------------
template <int EPI>
__global__ __launch_bounds__(256) void gemm_abt(
    const float* __restrict__ A, int lda, const float* __restrict__ B, int ldb,
    float* __restrict__ C, int ldc, int N, int K,
    const float* __restrict__ bias) {
  __shared__ float As[16][68];
  __shared__ float Bs[16][68];
  const int tid = threadIdx.x;
  const int tx = tid & 15;
  const int ty = tid >> 4;
  const int m0 = blockIdx.y * 64;
  const int n0 = blockIdx.x * 64;
  const int lk = tid & 15;   // k within tile
  const int lr = tid >> 4;   // row base within tile

  float acc[4][4];
#pragma unroll
  for (int i = 0; i < 4; ++i)
#pragma unroll
    for (int j = 0; j < 4; ++j) acc[i][j] = 0.0f;

  for (int k0 = 0; k0 < K; k0 += 16) {
#pragma unroll
    for (int i = 0; i < 4; ++i) {
      As[lk][lr + 16 * i] =
          A[(size_t)(m0 + lr + 16 * i) * lda + (k0 + lk)];
    }
#pragma unroll
    for (int i = 0; i < 4; ++i) {
      const int n = n0 + lr + 16 * i;
      Bs[lk][lr + 16 * i] =
          (n < N) ? B[(size_t)n * ldb + (k0 + lk)] : 0.0f;
    }
    __syncthreads();
#pragma unroll
    for (int k = 0; k < 16; ++k) {
      const float4 av = *reinterpret_cast<const float4*>(&As[k][ty * 4]);
      const float4 bv = *reinterpret_cast<const float4*>(&Bs[k][tx * 4]);
      const float a[4] = {av.x, av.y, av.z, av.w};
      const float b[4] = {bv.x, bv.y, bv.z, bv.w};
#pragma unroll
      for (int i = 0; i < 4; ++i)
#pragma unroll
        for (int j = 0; j < 4; ++j) acc[i][j] += a[i] * b[j];
    }
    __syncthreads();
  }

#pragma unroll
  for (int i = 0; i < 4; ++i) {
    const int m = m0 + ty * 4 + i;
#pragma unroll
    for (int j = 0; j < 4; ++j) {
      const int n = n0 + tx * 4 + j;
      if (n < N) {
        float v = acc[i][j];
        if (EPI == 1) {
          v += bias[n];
          v = (v > 20.0f) ? v : log1pf(__expf(v));
        } else if (EPI == 2) {
          v += C[(size_t)m * ldc + n];
        }
        C[(size_t)m * ldc + n] = v;
      }
    }
  }
}

// ---------------------------------------------------------------------------
// Causal depthwise conv (width 4) + bias + SiLU on the xi half of xz.
// xz: [rows, 2*DI]; out: [rows, DI]. One thread per (row,d). rows are
// whole batch sequences, so chunk-local l = row % LL is correct.
// ---------------------------------------------------------------------------
__global__ __launch_bounds__(256) void conv_silu_kernel(
    const float* __restrict__ xz, const float* __restrict__ w,
    const float* __restrict__ b, float* __restrict__ out) {
  const int idx = blockIdx.x * 256 + threadIdx.x;  // over rows*DI
  const int d = idx & (DI - 1);
  const int bl = idx >> 10;  // chunk-local row
  const int l = bl & (LL - 1);
  const float4 wv = *reinterpret_cast<const float4*>(w + (size_t)d * 4);
  float acc = b[d];
  const float wj[4] = {wv.x, wv.y, wv.z, wv.w};
#pragma unroll
  for (int j = 0; j < 4; ++j) {
    const int ls = l - 3 + j;
    if (ls >= 0) acc += wj[j] * xz[(size_t)(bl - 3 + j) * (2 * DI) + d];
  }
  const float s = 1.0f / (1.0f + __expf(-acc));
  out[(size_t)bl * DI + d] = acc * s;
}

// ---------------------------------------------------------------------------
// Selective scan. 8 lanes per (b,d) channel; each lane owns 4 of 32 states.
// Block = 256 threads = 32 channels; grid = nb*DI/32 blocks (chunk-local b).
// ---------------------------------------------------------------------------
__global__ __launch_bounds__(256) void scan_kernel(
    const float* __restrict__ dtv, float* __restrict__ xc,
    const float* __restrict__ xdbl, const float* __restrict__ xz,
    const float* __restrict__ A_log, const float* __restrict__ Dskip) {
  const int tid = threadIdx.x;
  const int lane = tid & 7;   // n-group: states lane*4 .. lane*4+3
  const int grp = tid >> 3;   // 0..31 -> channel within block
  const int bid = blockIdx.x;
  const int b = bid >> 5;                  // chunk-local batch
  const int d = ((bid & 31) << 5) + grp;

  float Ar[4];
#pragma unroll
  for (int s = 0; s < 4; ++s)
    Ar[s] = -__expf(A_log[(size_t)d * DS + lane * 4 + s]);
  float h0 = 0.f, h1 = 0.f, h2 = 0.f, h3 = 0.f;
  const float dsk = Dskip[d];
  const size_t rowbase = (size_t)b * LL;

  for (int l = 0; l < LL; ++l) {
    const size_t r = rowbase + l;
    const float dt = dtv[r * DI + d];
    const float x = xc[r * DI + d];
    const float4 Bv =
        *reinterpret_cast<const float4*>(xdbl + r * 96 + DR + lane * 4);
    const float4 Cv =
        *reinterpret_cast<const float4*>(xdbl + r * 96 + DR + DS + lane * 4);
    const float dtx = dt * x;
    h0 = __expf(dt * Ar[0]) * h0 + dtx * Bv.x;
    h1 = __expf(dt * Ar[1]) * h1 + dtx * Bv.y;
    h2 = __expf(dt * Ar[2]) * h2 + dtx * Bv.z;
    h3 = __expf(dt * Ar[3]) * h3 + dtx * Bv.w;
    float y = h0 * Cv.x + h1 * Cv.y + h2 * Cv.z + h3 * Cv.w;
    y += __shfl_xor(y, 1, 8);
    y += __shfl_xor(y, 2, 8);
    y += __shfl_xor(y, 4, 8);
    if (lane == 0) {
      const float z = xz[r * (2 * DI) + DI + d];
      const float g = z / (1.0f + __expf(-z));
      xc[r * DI + d] = (y + x * dsk) * g;
    }
  }
}

// ---------------------------------------------------------------------------
extern "C" void kernel_launch(void* const* d_in, const int* in_sizes, int n_in,
                              void* d_out, int out_size, void* d_ws,
                              size_t ws_size, hipStream_t stream) {
  const float* x = (const float*)d_in[0];
  const float* in_w = (const float*)d_in[1];
  const float* conv_w = (const float*)d_in[2];
  const float* conv_b = (const float*)d_in[3];
  const float* xp_w = (const float*)d_in[4];
  const float* dt_w = (const float*)d_in[5];
  const float* dt_b = (const float*)d_in[6];
  const float* A_log = (const float*)d_in[7];
  const float* Dsk = (const float*)d_in[8];
  const float* out_w = (const float*)d_in[9];
  const float* norm_w = (const float*)d_in[10];
  float* out = (float*)d_out;

  // Workspace: per-row floats = xz(2048) + xc(1024) + xdbl(96) + dtv(1024).
  // xn (rmsnorm out, 512/row, dead after in_proj) aliases the dtv buffer
  // (written only later by dt_proj).
  const size_t per_row_floats = 2 * DI + DI + 96 + DI;  // 4192
  int nchunk = 1;
  while (nchunk < 8 &&
         (size_t)(NROWS / nchunk) * per_row_floats * sizeof(float) > ws_size)
    nchunk <<= 1;
  const int nb = BB / nchunk;     // batches per chunk
  const int rows = nb * LL;       // rows per chunk

  float* ws = (float*)d_ws;
  float* xz = ws;                                  // rows*2*DI
  float* xc = xz + (size_t)rows * 2 * DI;          // rows*DI
  float* xdbl = xc + (size_t)rows * DI;            // rows*96
  float* dtv = xdbl + (size_t)rows * 96;           // rows*DI
  float* xn = dtv;                                 // alias (rows*DM <= rows*DI)

  // residual stream lives in d_out
  hipMemcpyAsync(out, x, (size_t)NROWS * DM * sizeof(float),
                 hipMemcpyDeviceToDevice, stream);

  for (int layer = 0; layer < NL; ++layer) {
    const float* l_inw = in_w + (size_t)layer * 2 * DI * DM;
    const float* l_cw = conv_w + (size_t)layer * DI * 4;
    const float* l_cb = conv_b + (size_t)layer * DI;
    const float* l_xpw = xp_w + (size_t)layer * 96 * DI;
    const float* l_dtw = dt_w + (size_t)layer * DI * DR;
    const float* l_dtb = dt_b + (size_t)layer * DI;
    const float* l_al = A_log + (size_t)layer * DI * DS;
    const float* l_dsk = Dsk + (size_t)layer * DI;
    const float* l_ow = out_w + (size_t)layer * DM * DI;
    const float* l_nw = norm_w + (size_t)layer * DM;

    for (int c = 0; c < nchunk; ++c) {
      float* res = out + (size_t)c * rows * DM;  // residual rows of this chunk

      rmsnorm_kernel<<<rows, 256, 0, stream>>>(res, l_nw, xn);

      // in_proj: [rows,512] x [2048,512]^T -> [rows,2048]
      gemm_abt<0><<<dim3(2 * DI / 64, rows / 64), 256, 0, stream>>>(
          xn, DM, l_inw, DM, xz, 2 * DI, 2 * DI, DM, nullptr);

      conv_silu_kernel<<<(rows * DI) / 256, 256, 0, stream>>>(xz, l_cw, l_cb,
                                                              xc);

      // x_proj: [rows,1024] x [96,1024]^T -> [rows,96]
      gemm_abt<0><<<dim3(2, rows / 64), 256, 0, stream>>>(
          xc, DI, l_xpw, DI, xdbl, 96, 96, DI, nullptr);

      // dt_proj(+softplus): [rows,32] x [1024,32]^T -> [rows,1024]
      gemm_abt<1><<<dim3(DI / 64, rows / 64), 256, 0, stream>>>(
          xdbl, 96, l_dtw, DR, dtv, DI, DI, DR, l_dtb);

      // selective scan (writes gated y in-place into xc)
      scan_kernel<<<(nb * DI) / 32, 256, 0, stream>>>(dtv, xc, xdbl, xz, l_al,
                                                      l_dsk);

      // out_proj + residual: res += [rows,1024] x [512,1024]^T
      gemm_abt<2><<<dim3(DM / 64, rows / 64), 256, 0, stream>>>(
          xc, DI, l_ow, DI, res, DM, DM, DI, nullptr);
    }
  }
}

// Round 3
// 25317.740 us; speedup vs baseline: 1.2997x; 1.2997x over previous
//
#include <hip/hip_runtime.h>
#include <hip/hip_bf16.h>
#include <cmath>

#define NL 8
#define BB 8
#define LL 2048
#define DM 512
#define DI 1024
#define DS 32
#define DR 32
#define NROWS (BB * LL)   // 16384

typedef __bf16 bf16x8 __attribute__((ext_vector_type(8)));
typedef float f32x4 __attribute__((ext_vector_type(4)));

// ---------------------------------------------------------------------------
// RMSNorm: one block (256 thr) per row of 512. float2 per thread.
// ---------------------------------------------------------------------------
__global__ __launch_bounds__(256) void rmsnorm_kernel(
    const float* __restrict__ x, const float* __restrict__ w,
    float* __restrict__ out) {
  const int row = blockIdx.x;
  const int tid = threadIdx.x;
  const float2 v = reinterpret_cast<const float2*>(x + (size_t)row * DM)[tid];
  float ss = v.x * v.x + v.y * v.y;
#pragma unroll
  for (int off = 1; off < 64; off <<= 1) ss += __shfl_xor(ss, off, 64);
  __shared__ float smem[4];
  if ((tid & 63) == 0) smem[tid >> 6] = ss;
  __syncthreads();
  const float tot = smem[0] + smem[1] + smem[2] + smem[3];
  const float scale = rsqrtf(tot * (1.0f / DM) + 1e-5f);
  const float2 wv = reinterpret_cast<const float2*>(w)[tid];
  float2 o;
  o.x = v.x * scale * wv.x;
  o.y = v.y * scale * wv.y;
  reinterpret_cast<float2*>(out + (size_t)row * DM)[tid] = o;
}

// ---------------------------------------------------------------------------
// bf16 MFMA GEMM: C[M,N] = A[M,K] * B[N,K]^T, fp32 in/out, bf16 staging.
// 128x128 block tile, 4 waves (2x2), each wave 64x64 via 4x4 frags of
// mfma_f32_16x16x32_bf16. K multiple of 32, M,N multiples of 128.
// EPI 0: plain store; EPI 2: C += v.
// LDS row stride 40 bf16 (80B): frag reads are 2-way bank aliased (free).
// ---------------------------------------------------------------------------
template <int EPI>
__global__ __launch_bounds__(256) void gemm_mfma(
    const float* __restrict__ A, int lda, const float* __restrict__ B, int ldb,
    float* __restrict__ C, int ldc, int K) {
  constexpr int LDSS = 40;
  __shared__ __bf16 As[128 * LDSS];
  __shared__ __bf16 Bs[128 * LDSS];
  const int tid = threadIdx.x;
  const int wave = tid >> 6;
  const int lane = tid & 63;
  const int wm = (wave >> 1) * 64;
  const int wn = (wave & 1) * 64;
  const int m0 = blockIdx.y * 128;
  const int n0 = blockIdx.x * 128;

  const int sr = tid >> 1;        // staging row 0..127
  const int sc = (tid & 1) * 16;  // staging col 0 or 16

  const int l15 = lane & 15;
  const int kg = lane >> 4;  // 0..3

  f32x4 acc[4][4] = {};

  for (int k0 = 0; k0 < K; k0 += 32) {
    {
      const float* sa = A + (size_t)(m0 + sr) * lda + k0 + sc;
      __bf16 tmp[16];
#pragma unroll
      for (int i = 0; i < 16; ++i) tmp[i] = (__bf16)sa[i];
      *(bf16x8*)&As[sr * LDSS + sc] = *(bf16x8*)&tmp[0];
      *(bf16x8*)&As[sr * LDSS + sc + 8] = *(bf16x8*)&tmp[8];
      const float* sb = B + (size_t)(n0 + sr) * ldb + k0 + sc;
#pragma unroll
      for (int i = 0; i < 16; ++i) tmp[i] = (__bf16)sb[i];
      *(bf16x8*)&Bs[sr * LDSS + sc] = *(bf16x8*)&tmp[0];
      *(bf16x8*)&Bs[sr * LDSS + sc + 8] = *(bf16x8*)&tmp[8];
    }
    __syncthreads();
    bf16x8 af[4], bfr[4];
#pragma unroll
    for (int i = 0; i < 4; ++i)
      af[i] = *(bf16x8*)&As[(wm + i * 16 + l15) * LDSS + kg * 8];
#pragma unroll
    for (int j = 0; j < 4; ++j)
      bfr[j] = *(bf16x8*)&Bs[(wn + j * 16 + l15) * LDSS + kg * 8];
#pragma unroll
    for (int i = 0; i < 4; ++i)
#pragma unroll
      for (int j = 0; j < 4; ++j)
        acc[i][j] = __builtin_amdgcn_mfma_f32_16x16x32_bf16(
            af[i], bfr[j], acc[i][j], 0, 0, 0);
    __syncthreads();
  }

  const int crow0 = kg * 4;
#pragma unroll
  for (int i = 0; i < 4; ++i) {
#pragma unroll
    for (int j = 0; j < 4; ++j) {
#pragma unroll
      for (int r = 0; r < 4; ++r) {
        const int m = m0 + wm + i * 16 + crow0 + r;
        const int n = n0 + wn + j * 16 + l15;
        float v = acc[i][j][r];
        if (EPI == 2) v += C[(size_t)m * ldc + n];
        C[(size_t)m * ldc + n] = v;
      }
    }
  }
}

// ---------------------------------------------------------------------------
// Tiled fp32 GEMM (kept for the skinny GEMMs: x_proj N=96, dt_proj K=32).
// EPI 0: plain store; EPI 1: softplus(v + bias[n]).
// ---------------------------------------------------------------------------
template <int EPI>
__global__ __launch_bounds__(256) void gemm_abt(
    const float* __restrict__ A, int lda, const float* __restrict__ B, int ldb,
    float* __restrict__ C, int ldc, int N, int K,
    const float* __restrict__ bias) {
  __shared__ float As[16][68];
  __shared__ float Bs[16][68];
  const int tid = threadIdx.x;
  const int tx = tid & 15;
  const int ty = tid >> 4;
  const int m0 = blockIdx.y * 64;
  const int n0 = blockIdx.x * 64;
  const int lk = tid & 15;
  const int lr = tid >> 4;

  float acc[4][4];
#pragma unroll
  for (int i = 0; i < 4; ++i)
#pragma unroll
    for (int j = 0; j < 4; ++j) acc[i][j] = 0.0f;

  for (int k0 = 0; k0 < K; k0 += 16) {
#pragma unroll
    for (int i = 0; i < 4; ++i) {
      As[lk][lr + 16 * i] = A[(size_t)(m0 + lr + 16 * i) * lda + (k0 + lk)];
    }
#pragma unroll
    for (int i = 0; i < 4; ++i) {
      const int n = n0 + lr + 16 * i;
      Bs[lk][lr + 16 * i] = (n < N) ? B[(size_t)n * ldb + (k0 + lk)] : 0.0f;
    }
    __syncthreads();
#pragma unroll
    for (int k = 0; k < 16; ++k) {
      const float4 av = *reinterpret_cast<const float4*>(&As[k][ty * 4]);
      const float4 bv = *reinterpret_cast<const float4*>(&Bs[k][tx * 4]);
      const float a[4] = {av.x, av.y, av.z, av.w};
      const float b[4] = {bv.x, bv.y, bv.z, bv.w};
#pragma unroll
      for (int i = 0; i < 4; ++i)
#pragma unroll
        for (int j = 0; j < 4; ++j) acc[i][j] += a[i] * b[j];
    }
    __syncthreads();
  }

#pragma unroll
  for (int i = 0; i < 4; ++i) {
    const int m = m0 + ty * 4 + i;
#pragma unroll
    for (int j = 0; j < 4; ++j) {
      const int n = n0 + tx * 4 + j;
      if (n < N) {
        float v = acc[i][j];
        if (EPI == 1) {
          v += bias[n];
          v = (v > 20.0f) ? v : log1pf(__expf(v));
        }
        C[(size_t)m * ldc + n] = v;
      }
    }
  }
}

// ---------------------------------------------------------------------------
// Causal depthwise conv (width 4) + bias + SiLU on the xi half of xz.
// ---------------------------------------------------------------------------
__global__ __launch_bounds__(256) void conv_silu_kernel(
    const float* __restrict__ xz, const float* __restrict__ w,
    const float* __restrict__ b, float* __restrict__ out) {
  const int idx = blockIdx.x * 256 + threadIdx.x;  // over rows*DI
  const int d = idx & (DI - 1);
  const int bl = idx >> 10;  // chunk-local row
  const int l = bl & (LL - 1);
  const float4 wv = *reinterpret_cast<const float4*>(w + (size_t)d * 4);
  float acc = b[d];
  const float wj[4] = {wv.x, wv.y, wv.z, wv.w};
#pragma unroll
  for (int j = 0; j < 4; ++j) {
    const int ls = l - 3 + j;
    if (ls >= 0) acc += wj[j] * xz[(size_t)(bl - 3 + j) * (2 * DI) + d];
  }
  const float s = 1.0f / (1.0f + __expf(-acc));
  out[(size_t)bl * DI + d] = acc * s;
}

// ---------------------------------------------------------------------------
// Selective scan v2: 1 state per lane (32 lanes/channel), 8 channels/block.
// Software-pipelined: prefetch iteration l+1's loads before computing l.
// Grid = nb * DI/8 blocks; block 256 threads.
// ---------------------------------------------------------------------------
__global__ __launch_bounds__(256) void scan_kernel(
    const float* __restrict__ dtv, float* __restrict__ xc,
    const float* __restrict__ xdbl, const float* __restrict__ xz,
    const float* __restrict__ A_log, const float* __restrict__ Dskip) {
  const int tid = threadIdx.x;
  const int s = tid & 31;    // state 0..31
  const int grp = tid >> 5;  // channel within block 0..7
  const int b = blockIdx.x >> 7;                  // DI/8 = 128 d-blocks
  const int d = ((blockIdx.x & 127) << 3) + grp;  // channel

  const float Ar = -__expf(A_log[(size_t)d * DS + s]);
  const float dsk = Dskip[d];
  float h = 0.f;
  const size_t rowbase = (size_t)b * LL;

  // prefetch l = 0
  float dt_c = dtv[rowbase * DI + d];
  float x_c = xc[rowbase * DI + d];
  float B_c = xdbl[rowbase * 96 + DR + s];
  float C_c = xdbl[rowbase * 96 + DR + DS + s];

  for (int l = 0; l < LL; ++l) {
    const size_t rn = rowbase + ((l + 1 < LL) ? l + 1 : l);
    const float dt_n = dtv[rn * DI + d];
    const float x_n = xc[rn * DI + d];
    const float B_n = xdbl[rn * 96 + DR + s];
    const float C_n = xdbl[rn * 96 + DR + DS + s];

    const float dA = __expf(dt_c * Ar);
    h = dA * h + (dt_c * x_c) * B_c;
    float y = h * C_c;
    y += __shfl_xor(y, 1, 32);
    y += __shfl_xor(y, 2, 32);
    y += __shfl_xor(y, 4, 32);
    y += __shfl_xor(y, 8, 32);
    y += __shfl_xor(y, 16, 32);
    if (s == 0) {
      const size_t r = rowbase + l;
      const float z = xz[r * (2 * DI) + DI + d];
      const float g = z / (1.0f + __expf(-z));
      xc[r * DI + d] = (y + x_c * dsk) * g;
    }
    dt_c = dt_n;
    x_c = x_n;
    B_c = B_n;
    C_c = C_n;
  }
}

// ---------------------------------------------------------------------------
extern "C" void kernel_launch(void* const* d_in, const int* in_sizes, int n_in,
                              void* d_out, int out_size, void* d_ws,
                              size_t ws_size, hipStream_t stream) {
  const float* x = (const float*)d_in[0];
  const float* in_w = (const float*)d_in[1];
  const float* conv_w = (const float*)d_in[2];
  const float* conv_b = (const float*)d_in[3];
  const float* xp_w = (const float*)d_in[4];
  const float* dt_w = (const float*)d_in[5];
  const float* dt_b = (const float*)d_in[6];
  const float* A_log = (const float*)d_in[7];
  const float* Dsk = (const float*)d_in[8];
  const float* out_w = (const float*)d_in[9];
  const float* norm_w = (const float*)d_in[10];
  float* out = (float*)d_out;

  // Workspace: per-row floats = xz(2048) + xc(1024) + xdbl(96) + dtv(1024).
  // xn (rmsnorm out, dead after in_proj) aliases the dtv buffer.
  const size_t per_row_floats = 2 * DI + DI + 96 + DI;  // 4192
  int nchunk = 1;
  while (nchunk < 8 &&
         (size_t)(NROWS / nchunk) * per_row_floats * sizeof(float) > ws_size)
    nchunk <<= 1;
  const int nb = BB / nchunk;  // batches per chunk
  const int rows = nb * LL;    // rows per chunk

  float* ws = (float*)d_ws;
  float* xz = ws;                          // rows*2*DI
  float* xc = xz + (size_t)rows * 2 * DI;  // rows*DI
  float* xdbl = xc + (size_t)rows * DI;    // rows*96
  float* dtv = xdbl + (size_t)rows * 96;   // rows*DI
  float* xn = dtv;                         // alias (rows*DM <= rows*DI)

  // residual stream lives in d_out
  hipMemcpyAsync(out, x, (size_t)NROWS * DM * sizeof(float),
                 hipMemcpyDeviceToDevice, stream);

  for (int layer = 0; layer < NL; ++layer) {
    const float* l_inw = in_w + (size_t)layer * 2 * DI * DM;
    const float* l_cw = conv_w + (size_t)layer * DI * 4;
    const float* l_cb = conv_b + (size_t)layer * DI;
    const float* l_xpw = xp_w + (size_t)layer * 96 * DI;
    const float* l_dtw = dt_w + (size_t)layer * DI * DR;
    const float* l_dtb = dt_b + (size_t)layer * DI;
    const float* l_al = A_log + (size_t)layer * DI * DS;
    const float* l_dsk = Dsk + (size_t)layer * DI;
    const float* l_ow = out_w + (size_t)layer * DM * DI;
    const float* l_nw = norm_w + (size_t)layer * DM;

    for (int c = 0; c < nchunk; ++c) {
      float* res = out + (size_t)c * rows * DM;

      rmsnorm_kernel<<<rows, 256, 0, stream>>>(res, l_nw, xn);

      // in_proj: [rows,512] x [2048,512]^T -> [rows,2048]  (bf16 MFMA)
      gemm_mfma<0><<<dim3(2 * DI / 128, rows / 128), 256, 0, stream>>>(
          xn, DM, l_inw, DM, xz, 2 * DI, DM);

      conv_silu_kernel<<<(rows * DI) / 256, 256, 0, stream>>>(xz, l_cw, l_cb,
                                                              xc);

      // x_proj: [rows,1024] x [96,1024]^T -> [rows,96]  (fp32)
      gemm_abt<0><<<dim3(2, rows / 64), 256, 0, stream>>>(
          xc, DI, l_xpw, DI, xdbl, 96, 96, DI, nullptr);

      // dt_proj(+softplus): [rows,32] x [1024,32]^T -> [rows,1024]  (fp32)
      gemm_abt<1><<<dim3(DI / 64, rows / 64), 256, 0, stream>>>(
          xdbl, 96, l_dtw, DR, dtv, DI, DI, DR, l_dtb);

      // selective scan (writes gated y in-place into xc)
      scan_kernel<<<nb * (DI / 8), 256, 0, stream>>>(dtv, xc, xdbl, xz, l_al,
                                                     l_dsk);

      // out_proj + residual: res += [rows,1024] x [512,1024]^T  (bf16 MFMA)
      gemm_mfma<2><<<dim3(DM / 128, rows / 128), 256, 0, stream>>>(
          xc, DI, l_ow, DI, res, DM, DI);
    }
  }
}

// Round 4
// 12261.029 us; speedup vs baseline: 2.6837x; 2.0649x over previous
//
#include <hip/hip_runtime.h>
#include <hip/hip_bf16.h>
#include <cmath>

#define NL 8
#define BB 8
#define LL 2048
#define DM 512
#define DI 1024
#define DS 32
#define DR 32
#define NROWS (BB * LL)   // 16384
#define NCH 16            // scan chunks per sequence
#define CH (LL / NCH)     // 128 timesteps per chunk

typedef __bf16 bf16x8 __attribute__((ext_vector_type(8)));
typedef float f32x4 __attribute__((ext_vector_type(4)));

// ---------------------------------------------------------------------------
// RMSNorm: one block (256 thr) per row of 512. float2 per thread.
// ---------------------------------------------------------------------------
__global__ __launch_bounds__(256) void rmsnorm_kernel(
    const float* __restrict__ x, const float* __restrict__ w,
    float* __restrict__ out) {
  const int row = blockIdx.x;
  const int tid = threadIdx.x;
  const float2 v = reinterpret_cast<const float2*>(x + (size_t)row * DM)[tid];
  float ss = v.x * v.x + v.y * v.y;
#pragma unroll
  for (int off = 1; off < 64; off <<= 1) ss += __shfl_xor(ss, off, 64);
  __shared__ float smem[4];
  if ((tid & 63) == 0) smem[tid >> 6] = ss;
  __syncthreads();
  const float tot = smem[0] + smem[1] + smem[2] + smem[3];
  const float scale = rsqrtf(tot * (1.0f / DM) + 1e-5f);
  const float2 wv = reinterpret_cast<const float2*>(w)[tid];
  float2 o;
  o.x = v.x * scale * wv.x;
  o.y = v.y * scale * wv.y;
  reinterpret_cast<float2*>(out + (size_t)row * DM)[tid] = o;
}

// ---------------------------------------------------------------------------
// bf16 MFMA GEMM: C[M,N] = A[M,K] * B[N,K]^T, fp32 in/out, bf16 staging.
// 128x128 block tile, 4 waves (2x2), each wave 64x64 via 4x4 frags of
// mfma_f32_16x16x32_bf16. K mult of 32, M mult of 128; N ragged via guard.
// EPI 0: plain store; EPI 2: C += v.
// ---------------------------------------------------------------------------
template <int EPI>
__global__ __launch_bounds__(256) void gemm_mfma(
    const float* __restrict__ A, int lda, const float* __restrict__ B, int ldb,
    float* __restrict__ C, int ldc, int N, int K) {
  constexpr int LDSS = 40;
  __shared__ __bf16 As[128 * LDSS];
  __shared__ __bf16 Bs[128 * LDSS];
  const int tid = threadIdx.x;
  const int wave = tid >> 6;
  const int lane = tid & 63;
  const int wm = (wave >> 1) * 64;
  const int wn = (wave & 1) * 64;
  const int m0 = blockIdx.y * 128;
  const int n0 = blockIdx.x * 128;

  const int sr = tid >> 1;        // staging row 0..127
  const int sc = (tid & 1) * 16;  // staging col 0 or 16

  const int l15 = lane & 15;
  const int kg = lane >> 4;  // 0..3

  f32x4 acc[4][4] = {};

  for (int k0 = 0; k0 < K; k0 += 32) {
    {
      const float* sa = A + (size_t)(m0 + sr) * lda + k0 + sc;
      __bf16 tmp[16];
#pragma unroll
      for (int i = 0; i < 16; ++i) tmp[i] = (__bf16)sa[i];
      *(bf16x8*)&As[sr * LDSS + sc] = *(bf16x8*)&tmp[0];
      *(bf16x8*)&As[sr * LDSS + sc + 8] = *(bf16x8*)&tmp[8];
      if (n0 + sr < N) {
        const float* sb = B + (size_t)(n0 + sr) * ldb + k0 + sc;
#pragma unroll
        for (int i = 0; i < 16; ++i) tmp[i] = (__bf16)sb[i];
      } else {
#pragma unroll
        for (int i = 0; i < 16; ++i) tmp[i] = (__bf16)0.0f;
      }
      *(bf16x8*)&Bs[sr * LDSS + sc] = *(bf16x8*)&tmp[0];
      *(bf16x8*)&Bs[sr * LDSS + sc + 8] = *(bf16x8*)&tmp[8];
    }
    __syncthreads();
    bf16x8 af[4], bfr[4];
#pragma unroll
    for (int i = 0; i < 4; ++i)
      af[i] = *(bf16x8*)&As[(wm + i * 16 + l15) * LDSS + kg * 8];
#pragma unroll
    for (int j = 0; j < 4; ++j)
      bfr[j] = *(bf16x8*)&Bs[(wn + j * 16 + l15) * LDSS + kg * 8];
#pragma unroll
    for (int i = 0; i < 4; ++i)
#pragma unroll
      for (int j = 0; j < 4; ++j)
        acc[i][j] = __builtin_amdgcn_mfma_f32_16x16x32_bf16(
            af[i], bfr[j], acc[i][j], 0, 0, 0);
    __syncthreads();
  }

  const int crow0 = kg * 4;
#pragma unroll
  for (int i = 0; i < 4; ++i) {
#pragma unroll
    for (int j = 0; j < 4; ++j) {
      const int n = n0 + wn + j * 16 + l15;
      if (n < N) {
#pragma unroll
        for (int r = 0; r < 4; ++r) {
          const int m = m0 + wm + i * 16 + crow0 + r;
          float v = acc[i][j][r];
          if (EPI == 2) v += C[(size_t)m * ldc + n];
          C[(size_t)m * ldc + n] = v;
        }
      }
    }
  }
}

// ---------------------------------------------------------------------------
// Tiled fp32 GEMM (kept for dt_proj: K=32). EPI 1: softplus(v + bias[n]).
// ---------------------------------------------------------------------------
template <int EPI>
__global__ __launch_bounds__(256) void gemm_abt(
    const float* __restrict__ A, int lda, const float* __restrict__ B, int ldb,
    float* __restrict__ C, int ldc, int N, int K,
    const float* __restrict__ bias) {
  __shared__ float As[16][68];
  __shared__ float Bs[16][68];
  const int tid = threadIdx.x;
  const int tx = tid & 15;
  const int ty = tid >> 4;
  const int m0 = blockIdx.y * 64;
  const int n0 = blockIdx.x * 64;
  const int lk = tid & 15;
  const int lr = tid >> 4;

  float acc[4][4];
#pragma unroll
  for (int i = 0; i < 4; ++i)
#pragma unroll
    for (int j = 0; j < 4; ++j) acc[i][j] = 0.0f;

  for (int k0 = 0; k0 < K; k0 += 16) {
#pragma unroll
    for (int i = 0; i < 4; ++i) {
      As[lk][lr + 16 * i] = A[(size_t)(m0 + lr + 16 * i) * lda + (k0 + lk)];
    }
#pragma unroll
    for (int i = 0; i < 4; ++i) {
      const int n = n0 + lr + 16 * i;
      Bs[lk][lr + 16 * i] = (n < N) ? B[(size_t)n * ldb + (k0 + lk)] : 0.0f;
    }
    __syncthreads();
#pragma unroll
    for (int k = 0; k < 16; ++k) {
      const float4 av = *reinterpret_cast<const float4*>(&As[k][ty * 4]);
      const float4 bv = *reinterpret_cast<const float4*>(&Bs[k][tx * 4]);
      const float a[4] = {av.x, av.y, av.z, av.w};
      const float b[4] = {bv.x, bv.y, bv.z, bv.w};
#pragma unroll
      for (int i = 0; i < 4; ++i)
#pragma unroll
        for (int j = 0; j < 4; ++j) acc[i][j] += a[i] * b[j];
    }
    __syncthreads();
  }

#pragma unroll
  for (int i = 0; i < 4; ++i) {
    const int m = m0 + ty * 4 + i;
#pragma unroll
    for (int j = 0; j < 4; ++j) {
      const int n = n0 + tx * 4 + j;
      if (n < N) {
        float v = acc[i][j];
        if (EPI == 1) {
          v += bias[n];
          v = (v > 20.0f) ? v : log1pf(__expf(v));
        }
        C[(size_t)m * ldc + n] = v;
      }
    }
  }
}

// ---------------------------------------------------------------------------
// Causal depthwise conv (width 4) + bias + SiLU on the xi half of xz.
// ---------------------------------------------------------------------------
__global__ __launch_bounds__(256) void conv_silu_kernel(
    const float* __restrict__ xz, const float* __restrict__ w,
    const float* __restrict__ b, float* __restrict__ out) {
  const int idx = blockIdx.x * 256 + threadIdx.x;  // over rows*DI
  const int d = idx & (DI - 1);
  const int bl = idx >> 10;  // chunk-local row
  const int l = bl & (LL - 1);
  const float4 wv = *reinterpret_cast<const float4*>(w + (size_t)d * 4);
  float acc = b[d];
  const float wj[4] = {wv.x, wv.y, wv.z, wv.w};
#pragma unroll
  for (int j = 0; j < 4; ++j) {
    const int ls = l - 3 + j;
    if (ls >= 0) acc += wj[j] * xz[(size_t)(bl - 3 + j) * (2 * DI) + d];
  }
  const float s = 1.0f / (1.0f + __expf(-acc));
  out[(size_t)bl * DI + d] = acc * s;
}

// ---------------------------------------------------------------------------
// Chunk-parallel selective scan.
// Layout: 32 lanes per channel (1 state each), 8 channels per 256-block.
// blockIdx.x = b*(NCH*128) + ch*128 + dblk   (phase1/phase3)
// phase1: local scan from h=0 over CH steps -> hend[b,ch,d,s], Sdt[b,ch,d].
// combine: serial over chunks: h_in_c = exp(A*Sdt_{c-1})*h_in_{c-1}+hend_{c-1}
// phase3: local scan seeded with h_in; computes y, gates, writes xc.
// ---------------------------------------------------------------------------
__global__ __launch_bounds__(256) void scan_phase1(
    const float* __restrict__ dtv, const float* __restrict__ xc,
    const float* __restrict__ xdbl, const float* __restrict__ A_log,
    float* __restrict__ hend, float* __restrict__ Sdt) {
  const int tid = threadIdx.x;
  const int s = tid & 31;
  const int grp = tid >> 5;
  const int dblk = blockIdx.x & 127;
  const int ch = (blockIdx.x >> 7) & (NCH - 1);
  const int b = blockIdx.x >> 11;
  const int d = (dblk << 3) + grp;

  const float Ar = -__expf(A_log[(size_t)d * DS + s]);
  float h = 0.f, sdt = 0.f;
  const size_t rowbase = (size_t)b * LL + (size_t)ch * CH;

  float dt_c = dtv[rowbase * DI + d];
  float x_c = xc[rowbase * DI + d];
  float B_c = xdbl[rowbase * 96 + DR + s];
  for (int l = 0; l < CH; ++l) {
    const size_t rn = rowbase + ((l + 1 < CH) ? l + 1 : l);
    const float dt_n = dtv[rn * DI + d];
    const float x_n = xc[rn * DI + d];
    const float B_n = xdbl[rn * 96 + DR + s];
    h = __expf(dt_c * Ar) * h + (dt_c * x_c) * B_c;
    sdt += dt_c;
    dt_c = dt_n;
    x_c = x_n;
    B_c = B_n;
  }
  const size_t cidx = ((size_t)b * NCH + ch) * DI + d;
  hend[cidx * DS + s] = h;
  if (s == 0) Sdt[cidx] = sdt;
}

__global__ __launch_bounds__(256) void scan_combine(
    const float* __restrict__ A_log, const float* __restrict__ Sdt,
    const float* __restrict__ hend, float* __restrict__ h_in) {
  const int tid = threadIdx.x;
  const int s = tid & 31;
  const int grp = tid >> 5;
  const int dblk = blockIdx.x & 127;
  const int b = blockIdx.x >> 7;
  const int d = (dblk << 3) + grp;
  const float Ar = -__expf(A_log[(size_t)d * DS + s]);
  float h = 0.f;
  for (int c = 0; c < NCH; ++c) {
    const size_t cidx = ((size_t)b * NCH + c) * DI + d;
    h_in[cidx * DS + s] = h;
    h = __expf(Ar * Sdt[cidx]) * h + hend[cidx * DS + s];
  }
}

__global__ __launch_bounds__(256) void scan_phase3(
    const float* __restrict__ dtv, float* __restrict__ xc,
    const float* __restrict__ xdbl, const float* __restrict__ xz,
    const float* __restrict__ A_log, const float* __restrict__ Dskip,
    const float* __restrict__ h_in) {
  const int tid = threadIdx.x;
  const int s = tid & 31;
  const int grp = tid >> 5;
  const int dblk = blockIdx.x & 127;
  const int ch = (blockIdx.x >> 7) & (NCH - 1);
  const int b = blockIdx.x >> 11;
  const int d = (dblk << 3) + grp;

  const float Ar = -__expf(A_log[(size_t)d * DS + s]);
  const float dsk = Dskip[d];
  const size_t cidx = ((size_t)b * NCH + ch) * DI + d;
  float h = h_in[cidx * DS + s];
  const size_t rowbase = (size_t)b * LL + (size_t)ch * CH;

  float dt_c = dtv[rowbase * DI + d];
  float x_c = xc[rowbase * DI + d];
  float B_c = xdbl[rowbase * 96 + DR + s];
  float C_c = xdbl[rowbase * 96 + DR + DS + s];

  for (int l = 0; l < CH; ++l) {
    const size_t rn = rowbase + ((l + 1 < CH) ? l + 1 : l);
    const float dt_n = dtv[rn * DI + d];
    const float x_n = xc[rn * DI + d];
    const float B_n = xdbl[rn * 96 + DR + s];
    const float C_n = xdbl[rn * 96 + DR + DS + s];

    h = __expf(dt_c * Ar) * h + (dt_c * x_c) * B_c;
    float y = h * C_c;
    y += __shfl_xor(y, 1, 32);
    y += __shfl_xor(y, 2, 32);
    y += __shfl_xor(y, 4, 32);
    y += __shfl_xor(y, 8, 32);
    y += __shfl_xor(y, 16, 32);
    if (s == 0) {
      const size_t r = rowbase + l;
      const float z = xz[r * (2 * DI) + DI + d];
      const float g = z / (1.0f + __expf(-z));
      xc[r * DI + d] = (y + x_c * dsk) * g;
    }
    dt_c = dt_n;
    x_c = x_n;
    B_c = B_n;
    C_c = C_n;
  }
}

// ---------------------------------------------------------------------------
extern "C" void kernel_launch(void* const* d_in, const int* in_sizes, int n_in,
                              void* d_out, int out_size, void* d_ws,
                              size_t ws_size, hipStream_t stream) {
  const float* x = (const float*)d_in[0];
  const float* in_w = (const float*)d_in[1];
  const float* conv_w = (const float*)d_in[2];
  const float* conv_b = (const float*)d_in[3];
  const float* xp_w = (const float*)d_in[4];
  const float* dt_w = (const float*)d_in[5];
  const float* dt_b = (const float*)d_in[6];
  const float* A_log = (const float*)d_in[7];
  const float* Dsk = (const float*)d_in[8];
  const float* out_w = (const float*)d_in[9];
  const float* norm_w = (const float*)d_in[10];
  float* out = (float*)d_out;

  // Workspace accounting (floats): per-row xz(2048)+xc(1024)+xdbl(96)+
  // dtv(1024, aliased by xn) = 4192, plus per-(batch) scan chunk state:
  // hend + h_in (2 * NCH*DI*DS) + Sdt (NCH*DI).
  int nchunk = 1;
  for (;;) {
    const int nb_try = BB / nchunk;
    const size_t rows_try = (size_t)nb_try * LL;
    const size_t need =
        (rows_try * 4192 + (size_t)nb_try * (2 * NCH * DI * DS + NCH * DI)) *
        sizeof(float);
    if (need <= ws_size || nchunk == 8) break;
    nchunk <<= 1;
  }
  const int nb = BB / nchunk;  // batches per chunk
  const int rows = nb * LL;    // rows per chunk

  float* ws = (float*)d_ws;
  float* xz = ws;                          // rows*2*DI
  float* xc = xz + (size_t)rows * 2 * DI;  // rows*DI
  float* xdbl = xc + (size_t)rows * DI;    // rows*96
  float* dtv = xdbl + (size_t)rows * 96;   // rows*DI
  float* xn = dtv;                         // alias (rows*DM <= rows*DI)
  float* hend = dtv + (size_t)rows * DI;   // nb*NCH*DI*DS
  float* h_in = hend + (size_t)nb * NCH * DI * DS;  // nb*NCH*DI*DS
  float* Sdt = h_in + (size_t)nb * NCH * DI * DS;   // nb*NCH*DI

  // residual stream lives in d_out
  hipMemcpyAsync(out, x, (size_t)NROWS * DM * sizeof(float),
                 hipMemcpyDeviceToDevice, stream);

  for (int layer = 0; layer < NL; ++layer) {
    const float* l_inw = in_w + (size_t)layer * 2 * DI * DM;
    const float* l_cw = conv_w + (size_t)layer * DI * 4;
    const float* l_cb = conv_b + (size_t)layer * DI;
    const float* l_xpw = xp_w + (size_t)layer * 96 * DI;
    const float* l_dtw = dt_w + (size_t)layer * DI * DR;
    const float* l_dtb = dt_b + (size_t)layer * DI;
    const float* l_al = A_log + (size_t)layer * DI * DS;
    const float* l_dsk = Dsk + (size_t)layer * DI;
    const float* l_ow = out_w + (size_t)layer * DM * DI;
    const float* l_nw = norm_w + (size_t)layer * DM;

    for (int c = 0; c < nchunk; ++c) {
      float* res = out + (size_t)c * rows * DM;

      rmsnorm_kernel<<<rows, 256, 0, stream>>>(res, l_nw, xn);

      // in_proj: [rows,512] x [2048,512]^T -> [rows,2048]  (bf16 MFMA)
      gemm_mfma<0><<<dim3(2 * DI / 128, rows / 128), 256, 0, stream>>>(
          xn, DM, l_inw, DM, xz, 2 * DI, 2 * DI, DM);

      conv_silu_kernel<<<(rows * DI) / 256, 256, 0, stream>>>(xz, l_cw, l_cb,
                                                              xc);

      // x_proj: [rows,1024] x [96,1024]^T -> [rows,96]  (bf16 MFMA, N-guard)
      gemm_mfma<0><<<dim3(1, rows / 128), 256, 0, stream>>>(
          xc, DI, l_xpw, DI, xdbl, 96, 96, DI);

      // dt_proj(+softplus): [rows,32] x [1024,32]^T -> [rows,1024]  (fp32)
      gemm_abt<1><<<dim3(DI / 64, rows / 64), 256, 0, stream>>>(
          xdbl, 96, l_dtw, DR, dtv, DI, DI, DR, l_dtb);

      // chunk-parallel selective scan (writes gated y in-place into xc)
      scan_phase1<<<nb * NCH * 128, 256, 0, stream>>>(dtv, xc, xdbl, l_al,
                                                      hend, Sdt);
      scan_combine<<<nb * 128, 256, 0, stream>>>(l_al, Sdt, hend, h_in);
      scan_phase3<<<nb * NCH * 128, 256, 0, stream>>>(dtv, xc, xdbl, xz, l_al,
                                                      l_dsk, h_in);

      // out_proj + residual: res += [rows,1024] x [512,1024]^T  (bf16 MFMA)
      gemm_mfma<2><<<dim3(DM / 128, rows / 128), 256, 0, stream>>>(
          xc, DI, l_ow, DI, res, DM, DM, DI);
    }
  }
}

// Round 5
// 6596.299 us; speedup vs baseline: 4.9883x; 1.8588x over previous
//
#include <hip/hip_runtime.h>
#include <hip/hip_bf16.h>
#include <cmath>

#define NL 8
#define BB 8
#define LL 2048
#define DM 512
#define DI 1024
#define DS 32
#define DR 32
#define NROWS (BB * LL)   // 16384
#define NCH 16            // scan chunks per sequence
#define CH (LL / NCH)     // 128 timesteps per chunk

typedef __bf16 bf16x8 __attribute__((ext_vector_type(8)));
typedef float f32x4 __attribute__((ext_vector_type(4)));

// ---------------------------------------------------------------------------
// RMSNorm: one block (256 thr) per row of 512. float2 per thread.
// ---------------------------------------------------------------------------
__global__ __launch_bounds__(256) void rmsnorm_kernel(
    const float* __restrict__ x, const float* __restrict__ w,
    float* __restrict__ out) {
  const int row = blockIdx.x;
  const int tid = threadIdx.x;
  const float2 v = reinterpret_cast<const float2*>(x + (size_t)row * DM)[tid];
  float ss = v.x * v.x + v.y * v.y;
#pragma unroll
  for (int off = 1; off < 64; off <<= 1) ss += __shfl_xor(ss, off, 64);
  __shared__ float smem[4];
  if ((tid & 63) == 0) smem[tid >> 6] = ss;
  __syncthreads();
  const float tot = smem[0] + smem[1] + smem[2] + smem[3];
  const float scale = rsqrtf(tot * (1.0f / DM) + 1e-5f);
  const float2 wv = reinterpret_cast<const float2*>(w)[tid];
  float2 o;
  o.x = v.x * scale * wv.x;
  o.y = v.y * scale * wv.y;
  reinterpret_cast<float2*>(out + (size_t)row * DM)[tid] = o;
}

// ---------------------------------------------------------------------------
// bf16 MFMA GEMM: C[M,N] = A[M,K] * B[N,K]^T, fp32 in/out, bf16 staging.
// 128x128 block tile, 4 waves (2x2), each wave 64x64 via 4x4 frags of
// mfma_f32_16x16x32_bf16. K mult of 32, M mult of 128; N ragged via guard.
// EPI 0: plain store; EPI 1: softplus(v + bias[n]); EPI 2: C += v.
// ---------------------------------------------------------------------------
template <int EPI>
__global__ __launch_bounds__(256) void gemm_mfma(
    const float* __restrict__ A, int lda, const float* __restrict__ B, int ldb,
    float* __restrict__ C, int ldc, int N, int K,
    const float* __restrict__ bias) {
  constexpr int LDSS = 40;
  __shared__ __bf16 As[128 * LDSS];
  __shared__ __bf16 Bs[128 * LDSS];
  const int tid = threadIdx.x;
  const int wave = tid >> 6;
  const int lane = tid & 63;
  const int wm = (wave >> 1) * 64;
  const int wn = (wave & 1) * 64;
  const int m0 = blockIdx.y * 128;
  const int n0 = blockIdx.x * 128;

  const int sr = tid >> 1;        // staging row 0..127
  const int sc = (tid & 1) * 16;  // staging col 0 or 16

  const int l15 = lane & 15;
  const int kg = lane >> 4;  // 0..3

  f32x4 acc[4][4] = {};

  for (int k0 = 0; k0 < K; k0 += 32) {
    {
      const float* sa = A + (size_t)(m0 + sr) * lda + k0 + sc;
      __bf16 tmp[16];
#pragma unroll
      for (int i = 0; i < 16; ++i) tmp[i] = (__bf16)sa[i];
      *(bf16x8*)&As[sr * LDSS + sc] = *(bf16x8*)&tmp[0];
      *(bf16x8*)&As[sr * LDSS + sc + 8] = *(bf16x8*)&tmp[8];
      if (n0 + sr < N) {
        const float* sb = B + (size_t)(n0 + sr) * ldb + k0 + sc;
#pragma unroll
        for (int i = 0; i < 16; ++i) tmp[i] = (__bf16)sb[i];
      } else {
#pragma unroll
        for (int i = 0; i < 16; ++i) tmp[i] = (__bf16)0.0f;
      }
      *(bf16x8*)&Bs[sr * LDSS + sc] = *(bf16x8*)&tmp[0];
      *(bf16x8*)&Bs[sr * LDSS + sc + 8] = *(bf16x8*)&tmp[8];
    }
    __syncthreads();
    bf16x8 af[4], bfr[4];
#pragma unroll
    for (int i = 0; i < 4; ++i)
      af[i] = *(bf16x8*)&As[(wm + i * 16 + l15) * LDSS + kg * 8];
#pragma unroll
    for (int j = 0; j < 4; ++j)
      bfr[j] = *(bf16x8*)&Bs[(wn + j * 16 + l15) * LDSS + kg * 8];
#pragma unroll
    for (int i = 0; i < 4; ++i)
#pragma unroll
      for (int j = 0; j < 4; ++j)
        acc[i][j] = __builtin_amdgcn_mfma_f32_16x16x32_bf16(
            af[i], bfr[j], acc[i][j], 0, 0, 0);
    __syncthreads();
  }

  const int crow0 = kg * 4;
#pragma unroll
  for (int i = 0; i < 4; ++i) {
#pragma unroll
    for (int j = 0; j < 4; ++j) {
      const int n = n0 + wn + j * 16 + l15;
      if (n < N) {
        float bj = (EPI == 1) ? bias[n] : 0.0f;
#pragma unroll
        for (int r = 0; r < 4; ++r) {
          const int m = m0 + wm + i * 16 + crow0 + r;
          float v = acc[i][j][r];
          if (EPI == 1) {
            v += bj;
            v = (v > 20.0f) ? v : log1pf(__expf(v));
          } else if (EPI == 2) {
            v += C[(size_t)m * ldc + n];
          }
          C[(size_t)m * ldc + n] = v;
        }
      }
    }
  }
}

// ---------------------------------------------------------------------------
// Causal depthwise conv (width 4) + bias + SiLU on the xi half of xz.
// ---------------------------------------------------------------------------
__global__ __launch_bounds__(256) void conv_silu_kernel(
    const float* __restrict__ xz, const float* __restrict__ w,
    const float* __restrict__ b, float* __restrict__ out) {
  const int idx = blockIdx.x * 256 + threadIdx.x;  // over rows*DI
  const int d = idx & (DI - 1);
  const int bl = idx >> 10;  // chunk-local row
  const int l = bl & (LL - 1);
  const float4 wv = *reinterpret_cast<const float4*>(w + (size_t)d * 4);
  float acc = b[d];
  const float wj[4] = {wv.x, wv.y, wv.z, wv.w};
#pragma unroll
  for (int j = 0; j < 4; ++j) {
    const int ls = l - 3 + j;
    if (ls >= 0) acc += wj[j] * xz[(size_t)(bl - 3 + j) * (2 * DI) + d];
  }
  const float s = 1.0f / (1.0f + __expf(-acc));
  out[(size_t)bl * DI + d] = acc * s;
}

// ---------------------------------------------------------------------------
// Chunk-parallel selective scan, 4 states per lane (8 lanes/channel).
// Block 256 thr = 32 channels. Grid = nb*NCH*(DI/32).
// blockIdx.x = (b*NCH + ch)*32 + dblk.
// phase1: local scan from h=0 -> hend[b,ch,d,0:32], Sdt[b,ch,d].
// combine: h_in_c = exp(A*Sdt_{c-1})*h_in_{c-1} + hend_{c-1}  (serial, tiny)
// phase3: local scan seeded with h_in; y, gate, write xc in place.
// ---------------------------------------------------------------------------
__global__ __launch_bounds__(256) void scan_phase1(
    const float* __restrict__ dtv, const float* __restrict__ xc,
    const float* __restrict__ xdbl, const float* __restrict__ A_log,
    float* __restrict__ hend, float* __restrict__ Sdt) {
  const int tid = threadIdx.x;
  const int lane = tid & 7;
  const int grp = tid >> 3;  // channel in block 0..31
  const int dblk = blockIdx.x & 31;
  const int ch = (blockIdx.x >> 5) & (NCH - 1);
  const int b = blockIdx.x >> 9;
  const int d = (dblk << 5) + grp;

  const float4 Av =
      *reinterpret_cast<const float4*>(A_log + (size_t)d * DS + lane * 4);
  const float Ar0 = -__expf(Av.x), Ar1 = -__expf(Av.y), Ar2 = -__expf(Av.z),
              Ar3 = -__expf(Av.w);
  float h0 = 0.f, h1 = 0.f, h2 = 0.f, h3 = 0.f, sdt = 0.f;
  const size_t rowbase = (size_t)b * LL + (size_t)ch * CH;

  const float* pdt = dtv + rowbase * DI + d;
  const float* px = xc + rowbase * DI + d;
  const float* pB = xdbl + rowbase * 96 + DR + (lane << 2);

  float dt_c = *pdt;
  float x_c = *px;
  float4 B_c = *reinterpret_cast<const float4*>(pB);

#define P1_STEP                              \
  {                                          \
    const float dtx = dt_c * x_c;            \
    sdt += dt_c;                             \
    h0 = __expf(dt_c * Ar0) * h0 + dtx * B_c.x; \
    h1 = __expf(dt_c * Ar1) * h1 + dtx * B_c.y; \
    h2 = __expf(dt_c * Ar2) * h2 + dtx * B_c.z; \
    h3 = __expf(dt_c * Ar3) * h3 + dtx * B_c.w; \
  }

  for (int l = 0; l < CH - 1; ++l) {
    pdt += DI;
    px += DI;
    pB += 96;
    const float dt_n = *pdt;
    const float x_n = *px;
    const float4 B_n = *reinterpret_cast<const float4*>(pB);
    P1_STEP
    dt_c = dt_n;
    x_c = x_n;
    B_c = B_n;
  }
  P1_STEP
#undef P1_STEP

  const size_t cidx = ((size_t)b * NCH + ch) * DI + d;
  float4 hv = {h0, h1, h2, h3};
  *reinterpret_cast<float4*>(hend + cidx * DS + (lane << 2)) = hv;
  if (lane == 0) Sdt[cidx] = sdt;
}

__global__ __launch_bounds__(256) void scan_combine(
    const float* __restrict__ A_log, const float* __restrict__ Sdt,
    const float* __restrict__ hend, float* __restrict__ h_in) {
  const int tid = threadIdx.x;
  const int s = tid & 31;
  const int grp = tid >> 5;
  const int dblk = blockIdx.x & 127;
  const int b = blockIdx.x >> 7;
  const int d = (dblk << 3) + grp;
  const float Ar = -__expf(A_log[(size_t)d * DS + s]);
  float h = 0.f;
  for (int c = 0; c < NCH; ++c) {
    const size_t cidx = ((size_t)b * NCH + c) * DI + d;
    h_in[cidx * DS + s] = h;
    h = __expf(Ar * Sdt[cidx]) * h + hend[cidx * DS + s];
  }
}

__global__ __launch_bounds__(256) void scan_phase3(
    const float* __restrict__ dtv, float* __restrict__ xc,
    const float* __restrict__ xdbl, const float* __restrict__ xz,
    const float* __restrict__ A_log, const float* __restrict__ Dskip,
    const float* __restrict__ h_in) {
  const int tid = threadIdx.x;
  const int lane = tid & 7;
  const int grp = tid >> 3;
  const int dblk = blockIdx.x & 31;
  const int ch = (blockIdx.x >> 5) & (NCH - 1);
  const int b = blockIdx.x >> 9;
  const int d = (dblk << 5) + grp;

  const float4 Av =
      *reinterpret_cast<const float4*>(A_log + (size_t)d * DS + lane * 4);
  const float Ar0 = -__expf(Av.x), Ar1 = -__expf(Av.y), Ar2 = -__expf(Av.z),
              Ar3 = -__expf(Av.w);
  const float dsk = Dskip[d];
  const size_t cidx = ((size_t)b * NCH + ch) * DI + d;
  const float4 hv =
      *reinterpret_cast<const float4*>(h_in + cidx * DS + (lane << 2));
  float h0 = hv.x, h1 = hv.y, h2 = hv.z, h3 = hv.w;
  const size_t rowbase = (size_t)b * LL + (size_t)ch * CH;

  const float* pdt = dtv + rowbase * DI + d;
  const float* px = xc + rowbase * DI + d;
  const float* pB = xdbl + rowbase * 96 + DR + (lane << 2);
  const float* pC = pB + DS;
  const float* pz = xz + rowbase * (2 * DI) + DI + d;
  float* pout = xc + rowbase * DI + d;

  float dt_c = *pdt;
  float x_c = *px;
  float4 B_c = *reinterpret_cast<const float4*>(pB);
  float4 C_c = *reinterpret_cast<const float4*>(pC);

#define P3_STEP                                           \
  {                                                       \
    const float dtx = dt_c * x_c;                         \
    h0 = __expf(dt_c * Ar0) * h0 + dtx * B_c.x;           \
    h1 = __expf(dt_c * Ar1) * h1 + dtx * B_c.y;           \
    h2 = __expf(dt_c * Ar2) * h2 + dtx * B_c.z;           \
    h3 = __expf(dt_c * Ar3) * h3 + dtx * B_c.w;           \
    float y = h0 * C_c.x + h1 * C_c.y + h2 * C_c.z + h3 * C_c.w; \
    y += __shfl_xor(y, 1, 8);                             \
    y += __shfl_xor(y, 2, 8);                             \
    y += __shfl_xor(y, 4, 8);                             \
    if (lane == 0) {                                      \
      const float z = *pz;                                \
      const float g = z / (1.0f + __expf(-z));            \
      *pout = (y + x_c * dsk) * g;                        \
    }                                                     \
    pz += 2 * DI;                                         \
    pout += DI;                                           \
  }

  for (int l = 0; l < CH - 1; ++l) {
    pdt += DI;
    px += DI;
    pB += 96;
    pC += 96;
    const float dt_n = *pdt;
    const float x_n = *px;
    const float4 B_n = *reinterpret_cast<const float4*>(pB);
    const float4 C_n = *reinterpret_cast<const float4*>(pC);
    P3_STEP
    dt_c = dt_n;
    x_c = x_n;
    B_c = B_n;
    C_c = C_n;
  }
  P3_STEP
#undef P3_STEP
}

// ---------------------------------------------------------------------------
extern "C" void kernel_launch(void* const* d_in, const int* in_sizes, int n_in,
                              void* d_out, int out_size, void* d_ws,
                              size_t ws_size, hipStream_t stream) {
  const float* x = (const float*)d_in[0];
  const float* in_w = (const float*)d_in[1];
  const float* conv_w = (const float*)d_in[2];
  const float* conv_b = (const float*)d_in[3];
  const float* xp_w = (const float*)d_in[4];
  const float* dt_w = (const float*)d_in[5];
  const float* dt_b = (const float*)d_in[6];
  const float* A_log = (const float*)d_in[7];
  const float* Dsk = (const float*)d_in[8];
  const float* out_w = (const float*)d_in[9];
  const float* norm_w = (const float*)d_in[10];
  float* out = (float*)d_out;

  // Workspace (floats): per-row xz(2048)+xc(1024)+xdbl(96)+dtv(1024, aliased
  // by xn) = 4192, plus per-batch scan state: hend+h_in (2*NCH*DI*DS) +
  // Sdt (NCH*DI).
  int nchunk = 1;
  for (;;) {
    const int nb_try = BB / nchunk;
    const size_t rows_try = (size_t)nb_try * LL;
    const size_t need =
        (rows_try * 4192 + (size_t)nb_try * (2 * NCH * DI * DS + NCH * DI)) *
        sizeof(float);
    if (need <= ws_size || nchunk == 8) break;
    nchunk <<= 1;
  }
  const int nb = BB / nchunk;  // batches per chunk
  const int rows = nb * LL;    // rows per chunk

  float* ws = (float*)d_ws;
  float* xz = ws;                          // rows*2*DI
  float* xc = xz + (size_t)rows * 2 * DI;  // rows*DI
  float* xdbl = xc + (size_t)rows * DI;    // rows*96
  float* dtv = xdbl + (size_t)rows * 96;   // rows*DI
  float* xn = dtv;                         // alias (rows*DM <= rows*DI)
  float* hend = dtv + (size_t)rows * DI;   // nb*NCH*DI*DS
  float* h_in = hend + (size_t)nb * NCH * DI * DS;  // nb*NCH*DI*DS
  float* Sdt = h_in + (size_t)nb * NCH * DI * DS;   // nb*NCH*DI

  // residual stream lives in d_out
  hipMemcpyAsync(out, x, (size_t)NROWS * DM * sizeof(float),
                 hipMemcpyDeviceToDevice, stream);

  for (int layer = 0; layer < NL; ++layer) {
    const float* l_inw = in_w + (size_t)layer * 2 * DI * DM;
    const float* l_cw = conv_w + (size_t)layer * DI * 4;
    const float* l_cb = conv_b + (size_t)layer * DI;
    const float* l_xpw = xp_w + (size_t)layer * 96 * DI;
    const float* l_dtw = dt_w + (size_t)layer * DI * DR;
    const float* l_dtb = dt_b + (size_t)layer * DI;
    const float* l_al = A_log + (size_t)layer * DI * DS;
    const float* l_dsk = Dsk + (size_t)layer * DI;
    const float* l_ow = out_w + (size_t)layer * DM * DI;
    const float* l_nw = norm_w + (size_t)layer * DM;

    for (int c = 0; c < nchunk; ++c) {
      float* res = out + (size_t)c * rows * DM;

      rmsnorm_kernel<<<rows, 256, 0, stream>>>(res, l_nw, xn);

      // in_proj: [rows,512] x [2048,512]^T -> [rows,2048]  (bf16 MFMA)
      gemm_mfma<0><<<dim3(2 * DI / 128, rows / 128), 256, 0, stream>>>(
          xn, DM, l_inw, DM, xz, 2 * DI, 2 * DI, DM, nullptr);

      conv_silu_kernel<<<(rows * DI) / 256, 256, 0, stream>>>(xz, l_cw, l_cb,
                                                              xc);

      // x_proj: [rows,1024] x [96,1024]^T -> [rows,96]  (bf16 MFMA, N-guard)
      gemm_mfma<0><<<dim3(1, rows / 128), 256, 0, stream>>>(
          xc, DI, l_xpw, DI, xdbl, 96, 96, DI, nullptr);

      // dt_proj(+softplus): [rows,32] x [1024,32]^T -> [rows,1024]  (MFMA)
      gemm_mfma<1><<<dim3(DI / 128, rows / 128), 256, 0, stream>>>(
          xdbl, 96, l_dtw, DR, dtv, DI, DI, DR, l_dtb);

      // chunk-parallel selective scan (writes gated y in-place into xc)
      scan_phase1<<<nb * NCH * (DI / 32), 256, 0, stream>>>(dtv, xc, xdbl,
                                                            l_al, hend, Sdt);
      scan_combine<<<nb * 128, 256, 0, stream>>>(l_al, Sdt, hend, h_in);
      scan_phase3<<<nb * NCH * (DI / 32), 256, 0, stream>>>(
          dtv, xc, xdbl, xz, l_al, l_dsk, h_in);

      // out_proj + residual: res += [rows,1024] x [512,1024]^T  (bf16 MFMA)
      gemm_mfma<2><<<dim3(DM / 128, rows / 128), 256, 0, stream>>>(
          xc, DI, l_ow, DI, res, DM, DM, DI, nullptr);
    }
  }
}

// Round 6
// 6353.321 us; speedup vs baseline: 5.1791x; 1.0382x over previous
//
#include <hip/hip_runtime.h>
#include <hip/hip_bf16.h>
#include <cmath>

#define NL 8
#define BB 8
#define LL 2048
#define DM 512
#define DI 1024
#define DS 32
#define DR 32
#define NROWS (BB * LL)   // 16384
#define NCH 16            // scan chunks per sequence
#define CH (LL / NCH)     // 128 timesteps per chunk

typedef __bf16 bf16x8 __attribute__((ext_vector_type(8)));
typedef float f32x4 __attribute__((ext_vector_type(4)));

#if defined(__has_builtin)
#if __has_builtin(__builtin_amdgcn_global_load_lds)
#define HAVE_GLL 1
#endif
#endif

// Stage 16 bytes per lane into LDS. lbase is the wave-uniform LDS base;
// HW (or the fallback) puts lane ln's 16B at lbase + ln*16B.
__device__ __forceinline__ void stage16(const __bf16* __restrict__ g,
                                        __bf16* __restrict__ lbase, int ln) {
#ifdef HAVE_GLL
  __builtin_amdgcn_global_load_lds(
      (const __attribute__((address_space(1))) void*)g,
      (__attribute__((address_space(3))) void*)lbase, 16, 0, 0);
#else
  *(bf16x8*)(lbase + ln * 8) = *(const bf16x8*)g;
#endif
}

// ---------------------------------------------------------------------------
// fp32 -> bf16 bulk convert (weights; once per launch). n4 = elems/4.
// ---------------------------------------------------------------------------
__global__ __launch_bounds__(256) void f2b_kernel(const float* __restrict__ s,
                                                  __bf16* __restrict__ d,
                                                  int n4) {
  int i = blockIdx.x * 256 + threadIdx.x;
  const int str = gridDim.x * 256;
  for (; i < n4; i += str) {
    const float4 v = reinterpret_cast<const float4*>(s)[i];
    union { __bf16 b[4]; uint2 u; } p;
    p.b[0] = (__bf16)v.x;
    p.b[1] = (__bf16)v.y;
    p.b[2] = (__bf16)v.z;
    p.b[3] = (__bf16)v.w;
    reinterpret_cast<uint2*>(d)[i] = p.u;
  }
}

// ---------------------------------------------------------------------------
// RMSNorm: one block (256 thr) per row of 512; writes bf16.
// ---------------------------------------------------------------------------
__global__ __launch_bounds__(256) void rmsnorm_kernel(
    const float* __restrict__ x, const float* __restrict__ w,
    __bf16* __restrict__ out) {
  const int row = blockIdx.x;
  const int tid = threadIdx.x;
  const float2 v = reinterpret_cast<const float2*>(x + (size_t)row * DM)[tid];
  float ss = v.x * v.x + v.y * v.y;
#pragma unroll
  for (int off = 1; off < 64; off <<= 1) ss += __shfl_xor(ss, off, 64);
  __shared__ float smem[4];
  if ((tid & 63) == 0) smem[tid >> 6] = ss;
  __syncthreads();
  const float tot = smem[0] + smem[1] + smem[2] + smem[3];
  const float scale = rsqrtf(tot * (1.0f / DM) + 1e-5f);
  const float2 wv = reinterpret_cast<const float2*>(w)[tid];
  union { __bf16 b[2]; unsigned u; } p;
  p.b[0] = (__bf16)(v.x * scale * wv.x);
  p.b[1] = (__bf16)(v.y * scale * wv.y);
  reinterpret_cast<unsigned*>(out + (size_t)row * DM)[tid] = p.u;
}

// ---------------------------------------------------------------------------
// bf16 MFMA GEMM (m97 structure): C[M,N] = A[M,K]*B[N,K]^T.
// A,B bf16; C fp32. 128x128 tile, 4 waves (2x2), 64x64/wave via 4x4 frags of
// mfma_f32_16x16x32_bf16. BK = 64 (or 32). Linear LDS [128][BK]; staging via
// global_load_lds width 16. M mult of 128; N ragged (clamp+guard).
// EPI 0: store; 1: softplus(v+bias[n]); 2: C += v; 3: store fp32 + bf16 Cb.
// ---------------------------------------------------------------------------
template <int BK, int EPI>
__global__ __launch_bounds__(256) void gemm_bf16(
    const __bf16* __restrict__ A, int lda, const __bf16* __restrict__ B,
    int ldb, float* __restrict__ C, int ldc, int N, int K,
    const float* __restrict__ bias, __bf16* __restrict__ Cb) {
  __shared__ __align__(16) __bf16 As[128 * BK];
  __shared__ __align__(16) __bf16 Bs[128 * BK];
  const int tid = threadIdx.x;
  const int wv = tid >> 6;   // wave 0..3
  const int ln = tid & 63;   // lane
  const int wm = (wv >> 1) * 64;
  const int wn = (wv & 1) * 64;
  const int m0 = blockIdx.y * 128;
  const int n0 = blockIdx.x * 128;
  const int l15 = ln & 15;
  const int kg = ln >> 4;  // 0..3
  constexpr int NIT = (128 * BK) / 2048;  // staging rounds per operand

  f32x4 acc[4][4] = {};

  for (int k0 = 0; k0 < K; k0 += BK) {
#pragma unroll
    for (int it = 0; it < NIT; ++it) {
      int row, col;
      if (BK == 64) {
        row = it * 32 + wv * 8 + (ln >> 3);
        col = (ln & 7) * 8;
      } else {
        row = it * 64 + wv * 16 + (ln >> 2);
        col = (ln & 3) * 8;
      }
      stage16(A + (size_t)(m0 + row) * lda + k0 + col,
              &As[it * 2048 + wv * 512], ln);
      int br = n0 + row;
      if (br > N - 1) br = N - 1;  // clamp (garbage cols never stored)
      stage16(B + (size_t)br * ldb + k0 + col, &Bs[it * 2048 + wv * 512], ln);
    }
    __syncthreads();  // drains vmcnt (global_load_lds) + lgkm
#pragma unroll
    for (int kk = 0; kk < BK / 32; ++kk) {
      bf16x8 af[4], bfr[4];
#pragma unroll
      for (int i = 0; i < 4; ++i)
        af[i] = *(const bf16x8*)&As[(wm + i * 16 + l15) * BK + kk * 32 + kg * 8];
#pragma unroll
      for (int j = 0; j < 4; ++j)
        bfr[j] = *(const bf16x8*)&Bs[(wn + j * 16 + l15) * BK + kk * 32 + kg * 8];
#pragma unroll
      for (int i = 0; i < 4; ++i)
#pragma unroll
        for (int j = 0; j < 4; ++j)
          acc[i][j] = __builtin_amdgcn_mfma_f32_16x16x32_bf16(
              af[i], bfr[j], acc[i][j], 0, 0, 0);
    }
    __syncthreads();
  }

  const int crow0 = kg * 4;
#pragma unroll
  for (int i = 0; i < 4; ++i) {
#pragma unroll
    for (int j = 0; j < 4; ++j) {
      const int n = n0 + wn + j * 16 + l15;
      if (n < N) {
        const float bj = (EPI == 1) ? bias[n] : 0.0f;
#pragma unroll
        for (int r = 0; r < 4; ++r) {
          const int m = m0 + wm + i * 16 + crow0 + r;
          float v = acc[i][j][r];
          if (EPI == 1) {
            v += bj;
            v = (v > 20.0f) ? v : log1pf(__expf(v));
          } else if (EPI == 2) {
            v += C[(size_t)m * ldc + n];
          }
          C[(size_t)m * ldc + n] = v;
          if (EPI == 3) Cb[(size_t)m * ldc + n] = (__bf16)v;
        }
      }
    }
  }
}

// ---------------------------------------------------------------------------
// Causal depthwise conv (width 4) + bias + SiLU; writes fp32 (scan) + bf16
// (x_proj A-operand).
// ---------------------------------------------------------------------------
__global__ __launch_bounds__(256) void conv_silu_kernel(
    const float* __restrict__ xz, const float* __restrict__ w,
    const float* __restrict__ b, float* __restrict__ out,
    __bf16* __restrict__ outb) {
  const int idx = blockIdx.x * 256 + threadIdx.x;  // over rows*DI
  const int d = idx & (DI - 1);
  const int bl = idx >> 10;  // chunk-local row
  const int l = bl & (LL - 1);
  const float4 wv = *reinterpret_cast<const float4*>(w + (size_t)d * 4);
  float acc = b[d];
  const float wj[4] = {wv.x, wv.y, wv.z, wv.w};
#pragma unroll
  for (int j = 0; j < 4; ++j) {
    const int ls = l - 3 + j;
    if (ls >= 0) acc += wj[j] * xz[(size_t)(bl - 3 + j) * (2 * DI) + d];
  }
  const float s = 1.0f / (1.0f + __expf(-acc));
  const float v = acc * s;
  out[(size_t)bl * DI + d] = v;
  outb[(size_t)bl * DI + d] = (__bf16)v;
}

// ---------------------------------------------------------------------------
// Chunk-parallel selective scan, 4 states per lane (8 lanes/channel).
// ---------------------------------------------------------------------------
__global__ __launch_bounds__(256) void scan_phase1(
    const float* __restrict__ dtv, const float* __restrict__ xc,
    const float* __restrict__ xdbl, const float* __restrict__ A_log,
    float* __restrict__ hend, float* __restrict__ Sdt) {
  const int tid = threadIdx.x;
  const int lane = tid & 7;
  const int grp = tid >> 3;  // channel in block 0..31
  const int dblk = blockIdx.x & 31;
  const int ch = (blockIdx.x >> 5) & (NCH - 1);
  const int b = blockIdx.x >> 9;
  const int d = (dblk << 5) + grp;

  const float4 Av =
      *reinterpret_cast<const float4*>(A_log + (size_t)d * DS + lane * 4);
  const float Ar0 = -__expf(Av.x), Ar1 = -__expf(Av.y), Ar2 = -__expf(Av.z),
              Ar3 = -__expf(Av.w);
  float h0 = 0.f, h1 = 0.f, h2 = 0.f, h3 = 0.f, sdt = 0.f;
  const size_t rowbase = (size_t)b * LL + (size_t)ch * CH;

  const float* pdt = dtv + rowbase * DI + d;
  const float* px = xc + rowbase * DI + d;
  const float* pB = xdbl + rowbase * 96 + DR + (lane << 2);

  float dt_c = *pdt;
  float x_c = *px;
  float4 B_c = *reinterpret_cast<const float4*>(pB);

#define P1_STEP                              \
  {                                          \
    const float dtx = dt_c * x_c;            \
    sdt += dt_c;                             \
    h0 = __expf(dt_c * Ar0) * h0 + dtx * B_c.x; \
    h1 = __expf(dt_c * Ar1) * h1 + dtx * B_c.y; \
    h2 = __expf(dt_c * Ar2) * h2 + dtx * B_c.z; \
    h3 = __expf(dt_c * Ar3) * h3 + dtx * B_c.w; \
  }

  for (int l = 0; l < CH - 1; ++l) {
    pdt += DI;
    px += DI;
    pB += 96;
    const float dt_n = *pdt;
    const float x_n = *px;
    const float4 B_n = *reinterpret_cast<const float4*>(pB);
    P1_STEP
    dt_c = dt_n;
    x_c = x_n;
    B_c = B_n;
  }
  P1_STEP
#undef P1_STEP

  const size_t cidx = ((size_t)b * NCH + ch) * DI + d;
  float4 hv = {h0, h1, h2, h3};
  *reinterpret_cast<float4*>(hend + cidx * DS + (lane << 2)) = hv;
  if (lane == 0) Sdt[cidx] = sdt;
}

__global__ __launch_bounds__(256) void scan_combine(
    const float* __restrict__ A_log, const float* __restrict__ Sdt,
    const float* __restrict__ hend, float* __restrict__ h_in) {
  const int tid = threadIdx.x;
  const int s = tid & 31;
  const int grp = tid >> 5;
  const int dblk = blockIdx.x & 127;
  const int b = blockIdx.x >> 7;
  const int d = (dblk << 3) + grp;
  const float Ar = -__expf(A_log[(size_t)d * DS + s]);
  float h = 0.f;
  for (int c = 0; c < NCH; ++c) {
    const size_t cidx = ((size_t)b * NCH + c) * DI + d;
    h_in[cidx * DS + s] = h;
    h = __expf(Ar * Sdt[cidx]) * h + hend[cidx * DS + s];
  }
}

__global__ __launch_bounds__(256) void scan_phase3(
    const float* __restrict__ dtv, const float* __restrict__ xc,
    const float* __restrict__ xdbl, const float* __restrict__ xz,
    const float* __restrict__ A_log, const float* __restrict__ Dskip,
    const float* __restrict__ h_in, __bf16* __restrict__ ygb) {
  const int tid = threadIdx.x;
  const int lane = tid & 7;
  const int grp = tid >> 3;
  const int dblk = blockIdx.x & 31;
  const int ch = (blockIdx.x >> 5) & (NCH - 1);
  const int b = blockIdx.x >> 9;
  const int d = (dblk << 5) + grp;

  const float4 Av =
      *reinterpret_cast<const float4*>(A_log + (size_t)d * DS + lane * 4);
  const float Ar0 = -__expf(Av.x), Ar1 = -__expf(Av.y), Ar2 = -__expf(Av.z),
              Ar3 = -__expf(Av.w);
  const float dsk = Dskip[d];
  const size_t cidx = ((size_t)b * NCH + ch) * DI + d;
  const float4 hv =
      *reinterpret_cast<const float4*>(h_in + cidx * DS + (lane << 2));
  float h0 = hv.x, h1 = hv.y, h2 = hv.z, h3 = hv.w;
  const size_t rowbase = (size_t)b * LL + (size_t)ch * CH;

  const float* pdt = dtv + rowbase * DI + d;
  const float* px = xc + rowbase * DI + d;
  const float* pB = xdbl + rowbase * 96 + DR + (lane << 2);
  const float* pC = pB + DS;
  const float* pz = xz + rowbase * (2 * DI) + DI + d;
  __bf16* pout = ygb + rowbase * DI + d;

  float dt_c = *pdt;
  float x_c = *px;
  float4 B_c = *reinterpret_cast<const float4*>(pB);
  float4 C_c = *reinterpret_cast<const float4*>(pC);

#define P3_STEP                                           \
  {                                                       \
    const float dtx = dt_c * x_c;                         \
    h0 = __expf(dt_c * Ar0) * h0 + dtx * B_c.x;           \
    h1 = __expf(dt_c * Ar1) * h1 + dtx * B_c.y;           \
    h2 = __expf(dt_c * Ar2) * h2 + dtx * B_c.z;           \
    h3 = __expf(dt_c * Ar3) * h3 + dtx * B_c.w;           \
    float y = h0 * C_c.x + h1 * C_c.y + h2 * C_c.z + h3 * C_c.w; \
    y += __shfl_xor(y, 1, 8);                             \
    y += __shfl_xor(y, 2, 8);                             \
    y += __shfl_xor(y, 4, 8);                             \
    if (lane == 0) {                                      \
      const float z = *pz;                                \
      const float g = z / (1.0f + __expf(-z));            \
      *pout = (__bf16)((y + x_c * dsk) * g);              \
    }                                                     \
    pz += 2 * DI;                                         \
    pout += DI;                                           \
  }

  for (int l = 0; l < CH - 1; ++l) {
    pdt += DI;
    px += DI;
    pB += 96;
    pC += 96;
    const float dt_n = *pdt;
    const float x_n = *px;
    const float4 B_n = *reinterpret_cast<const float4*>(pB);
    const float4 C_n = *reinterpret_cast<const float4*>(pC);
    P3_STEP
    dt_c = dt_n;
    x_c = x_n;
    B_c = B_n;
    C_c = C_n;
  }
  P3_STEP
#undef P3_STEP
}

// ---------------------------------------------------------------------------
extern "C" void kernel_launch(void* const* d_in, const int* in_sizes, int n_in,
                              void* d_out, int out_size, void* d_ws,
                              size_t ws_size, hipStream_t stream) {
  const float* x = (const float*)d_in[0];
  const float* in_w = (const float*)d_in[1];
  const float* conv_w = (const float*)d_in[2];
  const float* conv_b = (const float*)d_in[3];
  const float* xp_w = (const float*)d_in[4];
  const float* dt_w = (const float*)d_in[5];
  const float* dt_b = (const float*)d_in[6];
  const float* A_log = (const float*)d_in[7];
  const float* Dsk = (const float*)d_in[8];
  const float* out_w = (const float*)d_in[9];
  const float* norm_w = (const float*)d_in[10];
  float* out = (float*)d_out;

  // ---- bf16 weight mirrors (fixed region at start of ws) ----
  const size_t N_INW = (size_t)NL * 2 * DI * DM;   // 8.4M
  const size_t N_XPW = (size_t)NL * 96 * DI;       // 786K
  const size_t N_DTW = (size_t)NL * DI * DR;       // 262K
  const size_t N_OUW = (size_t)NL * DM * DI;       // 4.2M
  __bf16* inw_b = (__bf16*)d_ws;
  __bf16* xpw_b = inw_b + N_INW;
  __bf16* dtw_b = xpw_b + N_XPW;
  __bf16* outw_b = dtw_b + N_DTW;
  const size_t WBF = N_INW + N_XPW + N_DTW + N_OUW;  // bf16 elems (even)
  float* fbase = (float*)d_ws + WBF / 2;

  // ---- activation buffers (f32-equivalent units per row = 5264) ----
  int nchunk = 1;
  for (;;) {
    const int nb_try = BB / nchunk;
    const size_t rows_try = (size_t)nb_try * LL;
    const size_t need =
        (WBF / 2 + rows_try * 5264 +
         (size_t)nb_try * (2 * NCH * DI * DS + NCH * DI)) *
        sizeof(float);
    if (need <= ws_size || nchunk == 8) break;
    nchunk <<= 1;
  }
  const int nb = BB / nchunk;  // batches per chunk
  const int rows = nb * LL;    // rows per chunk

  float* xz = fbase;                       // rows*2048
  float* xc = xz + (size_t)rows * 2048;    // rows*1024
  float* xdbl = xc + (size_t)rows * 1024;  // rows*96
  float* dtv = xdbl + (size_t)rows * 96;   // rows*1024 (xn_b aliases start)
  __bf16* xnb = (__bf16*)dtv;              // rows*512 bf16 (dead before dtv)
  __bf16* xcb = (__bf16*)(dtv + (size_t)rows * 1024);     // rows*1024 bf16
  __bf16* xdblb = (__bf16*)((float*)xcb + (size_t)rows * 512);  // rows*96 bf16
  __bf16* ygb = (__bf16*)((float*)xdblb + (size_t)rows * 48);   // rows*1024 bf16
  float* hend = (float*)ygb + (size_t)rows * 512;  // nb*NCH*DI*DS
  float* h_in = hend + (size_t)nb * NCH * DI * DS;
  float* Sdt = h_in + (size_t)nb * NCH * DI * DS;

  // residual stream lives in d_out
  hipMemcpyAsync(out, x, (size_t)NROWS * DM * sizeof(float),
                 hipMemcpyDeviceToDevice, stream);

  // weight conversion (once per launch)
  f2b_kernel<<<4096, 256, 0, stream>>>(in_w, inw_b, (int)(N_INW / 4));
  f2b_kernel<<<768, 256, 0, stream>>>(xp_w, xpw_b, (int)(N_XPW / 4));
  f2b_kernel<<<256, 256, 0, stream>>>(dt_w, dtw_b, (int)(N_DTW / 4));
  f2b_kernel<<<2048, 256, 0, stream>>>(out_w, outw_b, (int)(N_OUW / 4));

  for (int layer = 0; layer < NL; ++layer) {
    const __bf16* l_inw = inw_b + (size_t)layer * 2 * DI * DM;
    const float* l_cw = conv_w + (size_t)layer * DI * 4;
    const float* l_cb = conv_b + (size_t)layer * DI;
    const __bf16* l_xpw = xpw_b + (size_t)layer * 96 * DI;
    const __bf16* l_dtw = dtw_b + (size_t)layer * DI * DR;
    const float* l_dtb = dt_b + (size_t)layer * DI;
    const float* l_al = A_log + (size_t)layer * DI * DS;
    const float* l_dsk = Dsk + (size_t)layer * DI;
    const __bf16* l_ow = outw_b + (size_t)layer * DM * DI;
    const float* l_nw = norm_w + (size_t)layer * DM;

    for (int c = 0; c < nchunk; ++c) {
      float* res = out + (size_t)c * rows * DM;

      rmsnorm_kernel<<<rows, 256, 0, stream>>>(res, l_nw, xnb);

      // in_proj: [rows,512] x [2048,512]^T -> [rows,2048]
      gemm_bf16<64, 0><<<dim3(16, rows / 128), 256, 0, stream>>>(
          xnb, DM, l_inw, DM, xz, 2 * DI, 2 * DI, DM, nullptr, nullptr);

      conv_silu_kernel<<<(rows * DI) / 256, 256, 0, stream>>>(xz, l_cw, l_cb,
                                                              xc, xcb);

      // x_proj: [rows,1024] x [96,1024]^T -> [rows,96] fp32 + bf16 mirror
      gemm_bf16<64, 3><<<dim3(1, rows / 128), 256, 0, stream>>>(
          xcb, DI, l_xpw, DI, xdbl, 96, 96, DI, nullptr, xdblb);

      // dt_proj(+softplus): [rows,32] x [1024,32]^T -> [rows,1024]
      gemm_bf16<32, 1><<<dim3(8, rows / 128), 256, 0, stream>>>(
          xdblb, 96, l_dtw, DR, dtv, DI, DI, DR, l_dtb, nullptr);

      // chunk-parallel selective scan -> bf16 gated y
      scan_phase1<<<nb * NCH * (DI / 32), 256, 0, stream>>>(dtv, xc, xdbl,
                                                            l_al, hend, Sdt);
      scan_combine<<<nb * 128, 256, 0, stream>>>(l_al, Sdt, hend, h_in);
      scan_phase3<<<nb * NCH * (DI / 32), 256, 0, stream>>>(
          dtv, xc, xdbl, xz, l_al, l_dsk, h_in, ygb);

      // out_proj + residual: res += [rows,1024] x [512,1024]^T
      gemm_bf16<64, 2><<<dim3(4, rows / 128), 256, 0, stream>>>(
          ygb, DI, l_ow, DI, res, DM, DM, DI, nullptr, nullptr);
    }
  }
}

// Round 7
// 5597.981 us; speedup vs baseline: 5.8779x; 1.1349x over previous
//
#include <hip/hip_runtime.h>
#include <hip/hip_bf16.h>
#include <cmath>

#define NL 8
#define BB 8
#define LL 2048
#define DM 512
#define DI 1024
#define DS 32
#define DR 32
#define NROWS (BB * LL)   // 16384
#define NCH 32            // scan chunks per sequence
#define CH (LL / NCH)     // 64 timesteps per chunk

typedef __bf16 bf16x8 __attribute__((ext_vector_type(8)));
typedef float f32x4 __attribute__((ext_vector_type(4)));

#if defined(__has_builtin)
#if __has_builtin(__builtin_amdgcn_global_load_lds)
#define HAVE_GLL 1
#endif
#endif

// Stage 16 bytes per lane into LDS. lbase is the wave-uniform LDS base;
// HW (or the fallback) puts lane ln's 16B at lbase + ln*16B.
__device__ __forceinline__ void stage16(const __bf16* __restrict__ g,
                                        __bf16* __restrict__ lbase, int ln) {
#ifdef HAVE_GLL
  __builtin_amdgcn_global_load_lds(
      (const __attribute__((address_space(1))) void*)g,
      (__attribute__((address_space(3))) void*)lbase, 16, 0, 0);
#else
  *(bf16x8*)(lbase + ln * 8) = *(const bf16x8*)g;
#endif
}

// ---------------------------------------------------------------------------
// fp32 -> bf16 bulk convert (weights; once per launch). n4 = elems/4.
// ---------------------------------------------------------------------------
__global__ __launch_bounds__(256) void f2b_kernel(const float* __restrict__ s,
                                                  __bf16* __restrict__ d,
                                                  int n4) {
  int i = blockIdx.x * 256 + threadIdx.x;
  const int str = gridDim.x * 256;
  for (; i < n4; i += str) {
    const float4 v = reinterpret_cast<const float4*>(s)[i];
    union { __bf16 b[4]; uint2 u; } p;
    p.b[0] = (__bf16)v.x;
    p.b[1] = (__bf16)v.y;
    p.b[2] = (__bf16)v.z;
    p.b[3] = (__bf16)v.w;
    reinterpret_cast<uint2*>(d)[i] = p.u;
  }
}

// ---------------------------------------------------------------------------
// RMSNorm: one block (256 thr) per row of 512; writes bf16.
// ---------------------------------------------------------------------------
__global__ __launch_bounds__(256) void rmsnorm_kernel(
    const float* __restrict__ x, const float* __restrict__ w,
    __bf16* __restrict__ out) {
  const int row = blockIdx.x;
  const int tid = threadIdx.x;
  const float2 v = reinterpret_cast<const float2*>(x + (size_t)row * DM)[tid];
  float ss = v.x * v.x + v.y * v.y;
#pragma unroll
  for (int off = 1; off < 64; off <<= 1) ss += __shfl_xor(ss, off, 64);
  __shared__ float smem[4];
  if ((tid & 63) == 0) smem[tid >> 6] = ss;
  __syncthreads();
  const float tot = smem[0] + smem[1] + smem[2] + smem[3];
  const float scale = rsqrtf(tot * (1.0f / DM) + 1e-5f);
  const float2 wv = reinterpret_cast<const float2*>(w)[tid];
  union { __bf16 b[2]; unsigned u; } p;
  p.b[0] = (__bf16)(v.x * scale * wv.x);
  p.b[1] = (__bf16)(v.y * scale * wv.y);
  reinterpret_cast<unsigned*>(out + (size_t)row * DM)[tid] = p.u;
}

// ---------------------------------------------------------------------------
// bf16 MFMA GEMM (m97 structure): C[M,N] = A[M,K]*B[N,K]^T.
// A,B bf16. 128x128 tile, 4 waves (2x2), 64x64/wave via 4x4 frags of
// mfma_f32_16x16x32_bf16. BK = 64 (or 32). Linear LDS [128][BK]; staging via
// global_load_lds width 16. M mult of 128; N ragged (clamp+guard).
// EPI 0: f32 store; 1: softplus(v+bias[n]) f32; 2: C += v (f32);
//     3: f32 C + bf16 Cb; 4: bf16 Cb only.
// ---------------------------------------------------------------------------
template <int BK, int EPI>
__global__ __launch_bounds__(256) void gemm_bf16(
    const __bf16* __restrict__ A, int lda, const __bf16* __restrict__ B,
    int ldb, float* __restrict__ C, int ldc, int N, int K,
    const float* __restrict__ bias, __bf16* __restrict__ Cb) {
  __shared__ __align__(16) __bf16 As[128 * BK];
  __shared__ __align__(16) __bf16 Bs[128 * BK];
  const int tid = threadIdx.x;
  const int wv = tid >> 6;   // wave 0..3
  const int ln = tid & 63;   // lane
  const int wm = (wv >> 1) * 64;
  const int wn = (wv & 1) * 64;
  const int m0 = blockIdx.y * 128;
  const int n0 = blockIdx.x * 128;
  const int l15 = ln & 15;
  const int kg = ln >> 4;  // 0..3
  constexpr int NIT = (128 * BK) / 2048;  // staging rounds per operand

  f32x4 acc[4][4] = {};

  for (int k0 = 0; k0 < K; k0 += BK) {
#pragma unroll
    for (int it = 0; it < NIT; ++it) {
      int row, col;
      if (BK == 64) {
        row = it * 32 + wv * 8 + (ln >> 3);
        col = (ln & 7) * 8;
      } else {
        row = it * 64 + wv * 16 + (ln >> 2);
        col = (ln & 3) * 8;
      }
      stage16(A + (size_t)(m0 + row) * lda + k0 + col,
              &As[it * 2048 + wv * 512], ln);
      int br = n0 + row;
      if (br > N - 1) br = N - 1;  // clamp (garbage cols never stored)
      stage16(B + (size_t)br * ldb + k0 + col, &Bs[it * 2048 + wv * 512], ln);
    }
    __syncthreads();  // drains vmcnt (global_load_lds) + lgkm
#pragma unroll
    for (int kk = 0; kk < BK / 32; ++kk) {
      bf16x8 af[4], bfr[4];
#pragma unroll
      for (int i = 0; i < 4; ++i)
        af[i] = *(const bf16x8*)&As[(wm + i * 16 + l15) * BK + kk * 32 + kg * 8];
#pragma unroll
      for (int j = 0; j < 4; ++j)
        bfr[j] = *(const bf16x8*)&Bs[(wn + j * 16 + l15) * BK + kk * 32 + kg * 8];
#pragma unroll
      for (int i = 0; i < 4; ++i)
#pragma unroll
        for (int j = 0; j < 4; ++j)
          acc[i][j] = __builtin_amdgcn_mfma_f32_16x16x32_bf16(
              af[i], bfr[j], acc[i][j], 0, 0, 0);
    }
    __syncthreads();
  }

  const int crow0 = kg * 4;
#pragma unroll
  for (int i = 0; i < 4; ++i) {
#pragma unroll
    for (int j = 0; j < 4; ++j) {
      const int n = n0 + wn + j * 16 + l15;
      if (n < N) {
        const float bj = (EPI == 1) ? bias[n] : 0.0f;
#pragma unroll
        for (int r = 0; r < 4; ++r) {
          const int m = m0 + wm + i * 16 + crow0 + r;
          float v = acc[i][j][r];
          if (EPI == 1) {
            v += bj;
            v = (v > 20.0f) ? v : log1pf(__expf(v));
          } else if (EPI == 2) {
            v += C[(size_t)m * ldc + n];
          }
          if (EPI == 4) {
            Cb[(size_t)m * ldc + n] = (__bf16)v;
          } else {
            C[(size_t)m * ldc + n] = v;
            if (EPI == 3) Cb[(size_t)m * ldc + n] = (__bf16)v;
          }
        }
      }
    }
  }
}

// ---------------------------------------------------------------------------
// Causal depthwise conv (width 4) + bias + SiLU on the xi half of bf16 xz.
// Writes bf16 xcb (scan x-input and x_proj A-operand).
// ---------------------------------------------------------------------------
__global__ __launch_bounds__(256) void conv_silu_kernel(
    const __bf16* __restrict__ xz, const float* __restrict__ w,
    const float* __restrict__ b, __bf16* __restrict__ outb) {
  const int idx = blockIdx.x * 256 + threadIdx.x;  // over rows*DI
  const int d = idx & (DI - 1);
  const int bl = idx >> 10;  // chunk-local row
  const int l = bl & (LL - 1);
  const float4 wv = *reinterpret_cast<const float4*>(w + (size_t)d * 4);
  float acc = b[d];
  const float wj[4] = {wv.x, wv.y, wv.z, wv.w};
#pragma unroll
  for (int j = 0; j < 4; ++j) {
    const int ls = l - 3 + j;
    if (ls >= 0)
      acc += wj[j] * (float)xz[(size_t)(bl - 3 + j) * (2 * DI) + d];
  }
  const float s = 1.0f / (1.0f + __expf(-acc));
  outb[(size_t)bl * DI + d] = (__bf16)(acc * s);
}

// ---------------------------------------------------------------------------
// Chunk-parallel selective scan v3: 8 states/lane, 4 lanes/channel.
// Block 256 thr = 64 channels. Grid = nb*NCH*(DI/64) = nb*512.
// blockIdx.x = ((b*NCH)+ch)*16 + dblk;  d = dblk*64 + (tid>>2); s0=(tid&3)*8.
// hend/h_in layout: [b][ch][s][DI] (coalesced in d).
// ---------------------------------------------------------------------------
__global__ __launch_bounds__(256) void scan_phase1(
    const float* __restrict__ dtv, const __bf16* __restrict__ xcb,
    const float* __restrict__ xdbl, const float* __restrict__ A_log,
    float* __restrict__ hend, float* __restrict__ Sdt) {
  const int tid = threadIdx.x;
  const int q = tid & 3;
  const int dloc = tid >> 2;
  const int dblk = blockIdx.x & 15;
  const int ch = (blockIdx.x >> 4) & (NCH - 1);
  const int b = blockIdx.x >> 9;
  const int d = dblk * 64 + dloc;
  const int s0 = q * 8;

  float Ar[8], h[8];
#pragma unroll
  for (int i = 0; i < 8; ++i) {
    Ar[i] = -__expf(A_log[(size_t)d * DS + s0 + i]);
    h[i] = 0.f;
  }
  float sdt = 0.f;
  const size_t rowbase = (size_t)b * LL + (size_t)ch * CH;
  const float* pdt = dtv + rowbase * DI + d;
  const __bf16* px = xcb + rowbase * DI + d;
  const float* pBC = xdbl + rowbase * 96 + DR + s0;

  for (int l = 0; l < CH; ++l) {
    const float dt = *pdt;
    const float x = (float)*px;
    const float4 B0 = *reinterpret_cast<const float4*>(pBC);
    const float4 B1 = *reinterpret_cast<const float4*>(pBC + 4);
    const float c = dt * x;
    sdt += dt;
    h[0] = __expf(dt * Ar[0]) * h[0] + c * B0.x;
    h[1] = __expf(dt * Ar[1]) * h[1] + c * B0.y;
    h[2] = __expf(dt * Ar[2]) * h[2] + c * B0.z;
    h[3] = __expf(dt * Ar[3]) * h[3] + c * B0.w;
    h[4] = __expf(dt * Ar[4]) * h[4] + c * B1.x;
    h[5] = __expf(dt * Ar[5]) * h[5] + c * B1.y;
    h[6] = __expf(dt * Ar[6]) * h[6] + c * B1.z;
    h[7] = __expf(dt * Ar[7]) * h[7] + c * B1.w;
    pdt += DI;
    px += DI;
    pBC += 96;
  }

  const size_t base = (((size_t)b * NCH + ch) * DS) * DI + d;
#pragma unroll
  for (int i = 0; i < 8; ++i) hend[base + (size_t)(s0 + i) * DI] = h[i];
  if (q == 0) Sdt[((size_t)b * NCH + ch) * DI + d] = sdt;
}

__global__ __launch_bounds__(256) void scan_combine(
    const float* __restrict__ A_log, const float* __restrict__ Sdt,
    const float* __restrict__ hend, float* __restrict__ h_in) {
  const int idx = blockIdx.x * 256 + threadIdx.x;  // over nb*DS*DI
  const int d = idx & (DI - 1);
  const int s = (idx >> 10) & (DS - 1);
  const int b = idx >> 15;
  const float Ar = -__expf(A_log[(size_t)d * DS + s]);
  float h = 0.f;
  for (int c = 0; c < NCH; ++c) {
    const size_t cidx = (size_t)b * NCH + c;
    h_in[(cidx * DS + s) * DI + d] = h;
    h = __expf(Ar * Sdt[cidx * DI + d]) * h + hend[(cidx * DS + s) * DI + d];
  }
}

__global__ __launch_bounds__(256) void scan_phase3(
    const float* __restrict__ dtv, const __bf16* __restrict__ xcb,
    const float* __restrict__ xdbl, const __bf16* __restrict__ xz,
    const float* __restrict__ A_log, const float* __restrict__ Dskip,
    const float* __restrict__ h_in, __bf16* __restrict__ ygb) {
  const int tid = threadIdx.x;
  const int q = tid & 3;
  const int dloc = tid >> 2;
  const int dblk = blockIdx.x & 15;
  const int ch = (blockIdx.x >> 4) & (NCH - 1);
  const int b = blockIdx.x >> 9;
  const int d = dblk * 64 + dloc;
  const int s0 = q * 8;

  float Ar[8], h[8];
  const size_t hbase = (((size_t)b * NCH + ch) * DS) * DI + d;
#pragma unroll
  for (int i = 0; i < 8; ++i) {
    Ar[i] = -__expf(A_log[(size_t)d * DS + s0 + i]);
    h[i] = h_in[hbase + (size_t)(s0 + i) * DI];
  }
  const float dsk = Dskip[d];
  const size_t rowbase = (size_t)b * LL + (size_t)ch * CH;
  const float* pdt = dtv + rowbase * DI + d;
  const __bf16* px = xcb + rowbase * DI + d;
  const float* pBC = xdbl + rowbase * 96 + DR + s0;
  const __bf16* pz = xz + rowbase * (2 * DI) + DI + d;
  __bf16* pyg = ygb + rowbase * DI + d;

  for (int l = 0; l < CH; ++l) {
    const float dt = *pdt;
    const float x = (float)*px;
    const float4 B0 = *reinterpret_cast<const float4*>(pBC);
    const float4 B1 = *reinterpret_cast<const float4*>(pBC + 4);
    const float4 C0 = *reinterpret_cast<const float4*>(pBC + DS);
    const float4 C1 = *reinterpret_cast<const float4*>(pBC + DS + 4);
    const float c = dt * x;
    h[0] = __expf(dt * Ar[0]) * h[0] + c * B0.x;
    h[1] = __expf(dt * Ar[1]) * h[1] + c * B0.y;
    h[2] = __expf(dt * Ar[2]) * h[2] + c * B0.z;
    h[3] = __expf(dt * Ar[3]) * h[3] + c * B0.w;
    h[4] = __expf(dt * Ar[4]) * h[4] + c * B1.x;
    h[5] = __expf(dt * Ar[5]) * h[5] + c * B1.y;
    h[6] = __expf(dt * Ar[6]) * h[6] + c * B1.z;
    h[7] = __expf(dt * Ar[7]) * h[7] + c * B1.w;
    float y01 = h[0] * C0.x + h[1] * C0.y;
    float y23 = h[2] * C0.z + h[3] * C0.w;
    float y45 = h[4] * C1.x + h[5] * C1.y;
    float y67 = h[6] * C1.z + h[7] * C1.w;
    float y = (y01 + y23) + (y45 + y67);
    y += __shfl_xor(y, 1, 64);
    y += __shfl_xor(y, 2, 64);
    if (q == 0) {
      const float z = (float)*pz;
      const float g = z / (1.0f + __expf(-z));
      *pyg = (__bf16)((y + x * dsk) * g);
    }
    pdt += DI;
    px += DI;
    pBC += 96;
    pz += 2 * DI;
    pyg += DI;
  }
}

// ---------------------------------------------------------------------------
extern "C" void kernel_launch(void* const* d_in, const int* in_sizes, int n_in,
                              void* d_out, int out_size, void* d_ws,
                              size_t ws_size, hipStream_t stream) {
  const float* x = (const float*)d_in[0];
  const float* in_w = (const float*)d_in[1];
  const float* conv_w = (const float*)d_in[2];
  const float* conv_b = (const float*)d_in[3];
  const float* xp_w = (const float*)d_in[4];
  const float* dt_w = (const float*)d_in[5];
  const float* dt_b = (const float*)d_in[6];
  const float* A_log = (const float*)d_in[7];
  const float* Dsk = (const float*)d_in[8];
  const float* out_w = (const float*)d_in[9];
  const float* norm_w = (const float*)d_in[10];
  float* out = (float*)d_out;

  // ---- bf16 weight mirrors (fixed region at start of ws) ----
  const size_t N_INW = (size_t)NL * 2 * DI * DM;   // 8.4M
  const size_t N_XPW = (size_t)NL * 96 * DI;       // 786K
  const size_t N_DTW = (size_t)NL * DI * DR;       // 262K
  const size_t N_OUW = (size_t)NL * DM * DI;       // 4.2M
  __bf16* inw_b = (__bf16*)d_ws;
  __bf16* xpw_b = inw_b + N_INW;
  __bf16* dtw_b = xpw_b + N_XPW;
  __bf16* outw_b = dtw_b + N_DTW;
  const size_t WBF = N_INW + N_XPW + N_DTW + N_OUW;  // bf16 elems (even)
  float* fbase = (float*)d_ws + WBF / 2;

  // ---- activations: per-row f32-equivalents:
  // xz(bf16,1024) + xcb(bf16,512) + xdbl(96) + xdblb(bf16,48) + dtv(1024) +
  // ygb(bf16,512) = 3216. Scan state per batch: 2*NCH*DS*DI + NCH*DI.
  int nchunk = 1;
  for (;;) {
    const int nb_try = BB / nchunk;
    const size_t rows_try = (size_t)nb_try * LL;
    const size_t need =
        (WBF / 2 + rows_try * 3216 +
         (size_t)nb_try * (2 * NCH * DS * DI + NCH * DI)) *
        sizeof(float);
    if (need <= ws_size || nchunk == 8) break;
    nchunk <<= 1;
  }
  const int nb = BB / nchunk;  // batches per chunk
  const int rows = nb * LL;    // rows per chunk

  __bf16* xzb = (__bf16*)fbase;                        // rows*2048 bf16
  __bf16* xcb = xzb + (size_t)rows * 2048;             // rows*1024 bf16
  float* xdbl = (float*)(xcb + (size_t)rows * 1024);   // rows*96 f32
  __bf16* xdblb = (__bf16*)(xdbl + (size_t)rows * 96); // rows*96 bf16
  float* dtv = (float*)(xdblb + (size_t)rows * 96);    // rows*1024 f32
  __bf16* xnb = (__bf16*)dtv;                          // alias rows*512 bf16
  __bf16* ygb = (__bf16*)(dtv + (size_t)rows * 1024);  // rows*1024 bf16
  float* hend = (float*)(ygb + (size_t)rows * 1024);   // nb*NCH*DS*DI
  float* h_in = hend + (size_t)nb * NCH * DS * DI;     // nb*NCH*DS*DI
  float* Sdt = h_in + (size_t)nb * NCH * DS * DI;      // nb*NCH*DI

  // residual stream lives in d_out
  hipMemcpyAsync(out, x, (size_t)NROWS * DM * sizeof(float),
                 hipMemcpyDeviceToDevice, stream);

  // weight conversion (once per launch)
  f2b_kernel<<<4096, 256, 0, stream>>>(in_w, inw_b, (int)(N_INW / 4));
  f2b_kernel<<<768, 256, 0, stream>>>(xp_w, xpw_b, (int)(N_XPW / 4));
  f2b_kernel<<<256, 256, 0, stream>>>(dt_w, dtw_b, (int)(N_DTW / 4));
  f2b_kernel<<<2048, 256, 0, stream>>>(out_w, outw_b, (int)(N_OUW / 4));

  for (int layer = 0; layer < NL; ++layer) {
    const __bf16* l_inw = inw_b + (size_t)layer * 2 * DI * DM;
    const float* l_cw = conv_w + (size_t)layer * DI * 4;
    const float* l_cb = conv_b + (size_t)layer * DI;
    const __bf16* l_xpw = xpw_b + (size_t)layer * 96 * DI;
    const __bf16* l_dtw = dtw_b + (size_t)layer * DI * DR;
    const float* l_dtb = dt_b + (size_t)layer * DI;
    const float* l_al = A_log + (size_t)layer * DI * DS;
    const float* l_dsk = Dsk + (size_t)layer * DI;
    const __bf16* l_ow = outw_b + (size_t)layer * DM * DI;
    const float* l_nw = norm_w + (size_t)layer * DM;

    for (int c = 0; c < nchunk; ++c) {
      float* res = out + (size_t)c * rows * DM;

      rmsnorm_kernel<<<rows, 256, 0, stream>>>(res, l_nw, xnb);

      // in_proj: [rows,512] x [2048,512]^T -> bf16 [rows,2048]
      gemm_bf16<64, 4><<<dim3(16, rows / 128), 256, 0, stream>>>(
          xnb, DM, l_inw, DM, nullptr, 2 * DI, 2 * DI, DM, nullptr, xzb);

      conv_silu_kernel<<<(rows * DI) / 256, 256, 0, stream>>>(xzb, l_cw, l_cb,
                                                              xcb);

      // x_proj: [rows,1024] x [96,1024]^T -> fp32 xdbl + bf16 xdblb
      gemm_bf16<64, 3><<<dim3(1, rows / 128), 256, 0, stream>>>(
          xcb, DI, l_xpw, DI, xdbl, 96, 96, DI, nullptr, xdblb);

      // dt_proj(+softplus): [rows,32] x [1024,32]^T -> fp32 [rows,1024]
      gemm_bf16<32, 1><<<dim3(8, rows / 128), 256, 0, stream>>>(
          xdblb, 96, l_dtw, DR, dtv, DI, DI, DR, l_dtb, nullptr);

      // chunk-parallel selective scan -> bf16 gated y
      scan_phase1<<<nb * NCH * 16, 256, 0, stream>>>(dtv, xcb, xdbl, l_al,
                                                     hend, Sdt);
      scan_combine<<<nb * 128, 256, 0, stream>>>(l_al, Sdt, hend, h_in);
      scan_phase3<<<nb * NCH * 16, 256, 0, stream>>>(dtv, xcb, xdbl, xzb,
                                                     l_al, l_dsk, h_in, ygb);

      // out_proj + residual: res += [rows,1024] x [512,1024]^T
      gemm_bf16<64, 2><<<dim3(4, rows / 128), 256, 0, stream>>>(
          ygb, DI, l_ow, DI, res, DM, DM, DI, nullptr, nullptr);
    }
  }
}

// Round 8
// 5294.038 us; speedup vs baseline: 6.2154x; 1.0574x over previous
//
#include <hip/hip_runtime.h>
#include <hip/hip_bf16.h>
#include <cmath>

#define NL 8
#define BB 8
#define LL 2048
#define DM 512
#define DI 1024
#define DS 32
#define DR 32
#define NROWS (BB * LL)   // 16384
#define NCH 32            // scan chunks per sequence
#define CH (LL / NCH)     // 64 timesteps per chunk

typedef __bf16 bf16x8 __attribute__((ext_vector_type(8)));
typedef float f32x4 __attribute__((ext_vector_type(4)));

#if defined(__has_builtin)
#if __has_builtin(__builtin_amdgcn_global_load_lds)
#define HAVE_GLL 1
#endif
#endif

// Stage 16 bytes per lane into LDS. lbase is the wave-uniform LDS base;
// HW (or the fallback) puts lane ln's 16B at lbase + ln*16B.
__device__ __forceinline__ void stage16(const __bf16* __restrict__ g,
                                        __bf16* __restrict__ lbase, int ln) {
#ifdef HAVE_GLL
  __builtin_amdgcn_global_load_lds(
      (const __attribute__((address_space(1))) void*)g,
      (__attribute__((address_space(3))) void*)lbase, 16, 0, 0);
#else
  *(bf16x8*)(lbase + ln * 8) = *(const bf16x8*)g;
#endif
}

// ---------------------------------------------------------------------------
// fp32 -> bf16 bulk convert (weights; once per launch). n4 = elems/4.
// ---------------------------------------------------------------------------
__global__ __launch_bounds__(256) void f2b_kernel(const float* __restrict__ s,
                                                  __bf16* __restrict__ d,
                                                  int n4) {
  int i = blockIdx.x * 256 + threadIdx.x;
  const int str = gridDim.x * 256;
  for (; i < n4; i += str) {
    const float4 v = reinterpret_cast<const float4*>(s)[i];
    union { __bf16 b[4]; uint2 u; } p;
    p.b[0] = (__bf16)v.x;
    p.b[1] = (__bf16)v.y;
    p.b[2] = (__bf16)v.z;
    p.b[3] = (__bf16)v.w;
    reinterpret_cast<uint2*>(d)[i] = p.u;
  }
}

// ---------------------------------------------------------------------------
// RMSNorm: one block (256 thr) per row of 512; writes bf16.
// ---------------------------------------------------------------------------
__global__ __launch_bounds__(256) void rmsnorm_kernel(
    const float* __restrict__ x, const float* __restrict__ w,
    __bf16* __restrict__ out) {
  const int row = blockIdx.x;
  const int tid = threadIdx.x;
  const float2 v = reinterpret_cast<const float2*>(x + (size_t)row * DM)[tid];
  float ss = v.x * v.x + v.y * v.y;
#pragma unroll
  for (int off = 1; off < 64; off <<= 1) ss += __shfl_xor(ss, off, 64);
  __shared__ float smem[4];
  if ((tid & 63) == 0) smem[tid >> 6] = ss;
  __syncthreads();
  const float tot = smem[0] + smem[1] + smem[2] + smem[3];
  const float scale = rsqrtf(tot * (1.0f / DM) + 1e-5f);
  const float2 wv = reinterpret_cast<const float2*>(w)[tid];
  union { __bf16 b[2]; unsigned u; } p;
  p.b[0] = (__bf16)(v.x * scale * wv.x);
  p.b[1] = (__bf16)(v.y * scale * wv.y);
  reinterpret_cast<unsigned*>(out + (size_t)row * DM)[tid] = p.u;
}

// ---------------------------------------------------------------------------
// bf16 MFMA GEMM (m97 structure): C[M,N] = A[M,K]*B[N,K]^T.
// A,B bf16. 128x128 tile, 4 waves (2x2), 64x64/wave via 4x4 frags of
// mfma_f32_16x16x32_bf16. BK = 64. Linear LDS [128][BK]; staging via
// global_load_lds width 16. M mult of 128; N ragged (clamp+guard).
// EPI 0: f32 store; 2: C += v (f32); 4: bf16 Cb only.
// ---------------------------------------------------------------------------
template <int BK, int EPI>
__global__ __launch_bounds__(256) void gemm_bf16(
    const __bf16* __restrict__ A, int lda, const __bf16* __restrict__ B,
    int ldb, float* __restrict__ C, int ldc, int N, int K,
    __bf16* __restrict__ Cb) {
  __shared__ __align__(16) __bf16 As[128 * BK];
  __shared__ __align__(16) __bf16 Bs[128 * BK];
  const int tid = threadIdx.x;
  const int wv = tid >> 6;   // wave 0..3
  const int ln = tid & 63;   // lane
  const int wm = (wv >> 1) * 64;
  const int wn = (wv & 1) * 64;
  const int m0 = blockIdx.y * 128;
  const int n0 = blockIdx.x * 128;
  const int l15 = ln & 15;
  const int kg = ln >> 4;  // 0..3
  constexpr int NIT = (128 * BK) / 2048;  // staging rounds per operand

  f32x4 acc[4][4] = {};

  for (int k0 = 0; k0 < K; k0 += BK) {
#pragma unroll
    for (int it = 0; it < NIT; ++it) {
      int row, col;
      if (BK == 64) {
        row = it * 32 + wv * 8 + (ln >> 3);
        col = (ln & 7) * 8;
      } else {
        row = it * 64 + wv * 16 + (ln >> 2);
        col = (ln & 3) * 8;
      }
      stage16(A + (size_t)(m0 + row) * lda + k0 + col,
              &As[it * 2048 + wv * 512], ln);
      int br = n0 + row;
      if (br > N - 1) br = N - 1;  // clamp (garbage cols never stored)
      stage16(B + (size_t)br * ldb + k0 + col, &Bs[it * 2048 + wv * 512], ln);
    }
    __syncthreads();  // drains vmcnt (global_load_lds) + lgkm
#pragma unroll
    for (int kk = 0; kk < BK / 32; ++kk) {
      bf16x8 af[4], bfr[4];
#pragma unroll
      for (int i = 0; i < 4; ++i)
        af[i] = *(const bf16x8*)&As[(wm + i * 16 + l15) * BK + kk * 32 + kg * 8];
#pragma unroll
      for (int j = 0; j < 4; ++j)
        bfr[j] = *(const bf16x8*)&Bs[(wn + j * 16 + l15) * BK + kk * 32 + kg * 8];
#pragma unroll
      for (int i = 0; i < 4; ++i)
#pragma unroll
        for (int j = 0; j < 4; ++j)
          acc[i][j] = __builtin_amdgcn_mfma_f32_16x16x32_bf16(
              af[i], bfr[j], acc[i][j], 0, 0, 0);
    }
    __syncthreads();
  }

  const int crow0 = kg * 4;
#pragma unroll
  for (int i = 0; i < 4; ++i) {
#pragma unroll
    for (int j = 0; j < 4; ++j) {
      const int n = n0 + wn + j * 16 + l15;
      if (n < N) {
#pragma unroll
        for (int r = 0; r < 4; ++r) {
          const int m = m0 + wm + i * 16 + crow0 + r;
          float v = acc[i][j][r];
          if (EPI == 2) v += C[(size_t)m * ldc + n];
          if (EPI == 4) {
            Cb[(size_t)m * ldc + n] = (__bf16)v;
          } else {
            C[(size_t)m * ldc + n] = v;
          }
        }
      }
    }
  }
}

// ---------------------------------------------------------------------------
// Causal depthwise conv (width 4) + bias + SiLU on the xi half of bf16 xz.
// Vectorized: one thread computes 8 adjacent d's. Writes bf16 xcb.
// ---------------------------------------------------------------------------
__global__ __launch_bounds__(256) void conv_silu_kernel(
    const __bf16* __restrict__ xz, const float* __restrict__ w,
    const float* __restrict__ b, __bf16* __restrict__ outb) {
  const int idx = blockIdx.x * 256 + threadIdx.x;  // over rows*DI/8
  const int d8 = (idx & 127) << 3;  // d base (0..1016 step 8)
  const int bl = idx >> 7;          // chunk-local row
  const int l = bl & (LL - 1);

  float acc[8];
  const float4 b01 = *reinterpret_cast<const float4*>(b + d8);
  const float4 b23 = *reinterpret_cast<const float4*>(b + d8 + 4);
  acc[0] = b01.x; acc[1] = b01.y; acc[2] = b01.z; acc[3] = b01.w;
  acc[4] = b23.x; acc[5] = b23.y; acc[6] = b23.z; acc[7] = b23.w;

#pragma unroll
  for (int j = 0; j < 4; ++j) {
    const int ls = l - 3 + j;
    if (ls >= 0) {
      const bf16x8 xv = *reinterpret_cast<const bf16x8*>(
          xz + (size_t)(bl - 3 + j) * (2 * DI) + d8);
#pragma unroll
      for (int i = 0; i < 8; ++i)
        acc[i] += w[(size_t)(d8 + i) * 4 + j] * (float)xv[i];
    }
  }
  bf16x8 o;
#pragma unroll
  for (int i = 0; i < 8; ++i) {
    const float s = 1.0f / (1.0f + __expf(-acc[i]));
    o[i] = (__bf16)(acc[i] * s);
  }
  *reinterpret_cast<bf16x8*>(outb + (size_t)bl * DI + d8) = o;
}

// ---------------------------------------------------------------------------
// Chunk-parallel selective scan v4: 8 states/lane, 4 lanes/channel, with
// dt computed IN-KERNEL from xdbl[:, 0:32] (dt_proj fused).
// Block 256 thr = 64 channels. Grid = nb*NCH*(DI/64) = nb*512.
// Lane q of a channel holds dt_w[d][8q:8q+8]; partial dot + 2x shfl_xor(4).
// hend/h_in layout: [b][ch][s][DI] (coalesced in d).
// ---------------------------------------------------------------------------
__device__ __forceinline__ float softplus_f(float v) {
  return (v > 20.0f) ? v : __logf(1.0f + __expf(v));
}

__global__ __launch_bounds__(256) void scan_phase1(
    const __bf16* __restrict__ xcb, const float* __restrict__ xdbl,
    const float* __restrict__ A_log, const float* __restrict__ dt_w,
    const float* __restrict__ dt_b, float* __restrict__ hend,
    float* __restrict__ Sdt) {
  const int tid = threadIdx.x;
  const int q = tid & 3;
  const int dloc = tid >> 2;
  const int dblk = blockIdx.x & 15;
  const int ch = (blockIdx.x >> 4) & (NCH - 1);
  const int b = blockIdx.x >> 9;
  const int d = dblk * 64 + dloc;
  const int s0 = q * 8;

  float Ar[8], h[8], wr[8];
  const float4 w0 = *reinterpret_cast<const float4*>(dt_w + (size_t)d * DR + s0);
  const float4 w1 =
      *reinterpret_cast<const float4*>(dt_w + (size_t)d * DR + s0 + 4);
  wr[0] = w0.x; wr[1] = w0.y; wr[2] = w0.z; wr[3] = w0.w;
  wr[4] = w1.x; wr[5] = w1.y; wr[6] = w1.z; wr[7] = w1.w;
  const float bias = dt_b[d];
#pragma unroll
  for (int i = 0; i < 8; ++i) {
    Ar[i] = -__expf(A_log[(size_t)d * DS + s0 + i]);
    h[i] = 0.f;
  }
  float sdt = 0.f;
  const size_t rowbase = (size_t)b * LL + (size_t)ch * CH;
  const __bf16* px = xcb + rowbase * DI + d;
  const float* pR = xdbl + rowbase * 96 + s0;  // dt_rank segment for lane q

  for (int l = 0; l < CH; ++l) {
    const float x = (float)*px;
    const float4 R0 = *reinterpret_cast<const float4*>(pR);
    const float4 R1 = *reinterpret_cast<const float4*>(pR + 4);
    const float4 B0 = *reinterpret_cast<const float4*>(pR + DR);
    const float4 B1 = *reinterpret_cast<const float4*>(pR + DR + 4);
    float p = wr[0] * R0.x + wr[1] * R0.y + wr[2] * R0.z + wr[3] * R0.w +
              wr[4] * R1.x + wr[5] * R1.y + wr[6] * R1.z + wr[7] * R1.w;
    p += __shfl_xor(p, 1, 4);
    p += __shfl_xor(p, 2, 4);
    const float dt = softplus_f(p + bias);
    const float c = dt * x;
    sdt += dt;
    h[0] = __expf(dt * Ar[0]) * h[0] + c * B0.x;
    h[1] = __expf(dt * Ar[1]) * h[1] + c * B0.y;
    h[2] = __expf(dt * Ar[2]) * h[2] + c * B0.z;
    h[3] = __expf(dt * Ar[3]) * h[3] + c * B0.w;
    h[4] = __expf(dt * Ar[4]) * h[4] + c * B1.x;
    h[5] = __expf(dt * Ar[5]) * h[5] + c * B1.y;
    h[6] = __expf(dt * Ar[6]) * h[6] + c * B1.z;
    h[7] = __expf(dt * Ar[7]) * h[7] + c * B1.w;
    px += DI;
    pR += 96;
  }

  const size_t base = (((size_t)b * NCH + ch) * DS) * DI + d;
#pragma unroll
  for (int i = 0; i < 8; ++i) hend[base + (size_t)(s0 + i) * DI] = h[i];
  if (q == 0) Sdt[((size_t)b * NCH + ch) * DI + d] = sdt;
}

__global__ __launch_bounds__(256) void scan_combine(
    const float* __restrict__ A_log, const float* __restrict__ Sdt,
    const float* __restrict__ hend, float* __restrict__ h_in) {
  const int idx = blockIdx.x * 256 + threadIdx.x;  // over nb*DS*DI
  const int d = idx & (DI - 1);
  const int s = (idx >> 10) & (DS - 1);
  const int b = idx >> 15;
  const float Ar = -__expf(A_log[(size_t)d * DS + s]);
  float h = 0.f;
  for (int c = 0; c < NCH; ++c) {
    const size_t cidx = (size_t)b * NCH + c;
    h_in[(cidx * DS + s) * DI + d] = h;
    h = __expf(Ar * Sdt[cidx * DI + d]) * h + hend[(cidx * DS + s) * DI + d];
  }
}

__global__ __launch_bounds__(256) void scan_phase3(
    const __bf16* __restrict__ xcb, const float* __restrict__ xdbl,
    const __bf16* __restrict__ xz, const float* __restrict__ A_log,
    const float* __restrict__ dt_w, const float* __restrict__ dt_b,
    const float* __restrict__ Dskip, const float* __restrict__ h_in,
    __bf16* __restrict__ ygb) {
  const int tid = threadIdx.x;
  const int q = tid & 3;
  const int dloc = tid >> 2;
  const int dblk = blockIdx.x & 15;
  const int ch = (blockIdx.x >> 4) & (NCH - 1);
  const int b = blockIdx.x >> 9;
  const int d = dblk * 64 + dloc;
  const int s0 = q * 8;

  float Ar[8], h[8], wr[8];
  const float4 w0 = *reinterpret_cast<const float4*>(dt_w + (size_t)d * DR + s0);
  const float4 w1 =
      *reinterpret_cast<const float4*>(dt_w + (size_t)d * DR + s0 + 4);
  wr[0] = w0.x; wr[1] = w0.y; wr[2] = w0.z; wr[3] = w0.w;
  wr[4] = w1.x; wr[5] = w1.y; wr[6] = w1.z; wr[7] = w1.w;
  const float bias = dt_b[d];
  const size_t hbase = (((size_t)b * NCH + ch) * DS) * DI + d;
#pragma unroll
  for (int i = 0; i < 8; ++i) {
    Ar[i] = -__expf(A_log[(size_t)d * DS + s0 + i]);
    h[i] = h_in[hbase + (size_t)(s0 + i) * DI];
  }
  const float dsk = Dskip[d];
  const size_t rowbase = (size_t)b * LL + (size_t)ch * CH;
  const __bf16* px = xcb + rowbase * DI + d;
  const float* pR = xdbl + rowbase * 96 + s0;
  const __bf16* pz = xz + rowbase * (2 * DI) + DI + d;
  __bf16* pyg = ygb + rowbase * DI + d;

  for (int l = 0; l < CH; ++l) {
    const float x = (float)*px;
    const float4 R0 = *reinterpret_cast<const float4*>(pR);
    const float4 R1 = *reinterpret_cast<const float4*>(pR + 4);
    const float4 B0 = *reinterpret_cast<const float4*>(pR + DR);
    const float4 B1 = *reinterpret_cast<const float4*>(pR + DR + 4);
    const float4 C0 = *reinterpret_cast<const float4*>(pR + DR + DS);
    const float4 C1 = *reinterpret_cast<const float4*>(pR + DR + DS + 4);
    float p = wr[0] * R0.x + wr[1] * R0.y + wr[2] * R0.z + wr[3] * R0.w +
              wr[4] * R1.x + wr[5] * R1.y + wr[6] * R1.z + wr[7] * R1.w;
    p += __shfl_xor(p, 1, 4);
    p += __shfl_xor(p, 2, 4);
    const float dt = softplus_f(p + bias);
    const float c = dt * x;
    h[0] = __expf(dt * Ar[0]) * h[0] + c * B0.x;
    h[1] = __expf(dt * Ar[1]) * h[1] + c * B0.y;
    h[2] = __expf(dt * Ar[2]) * h[2] + c * B0.z;
    h[3] = __expf(dt * Ar[3]) * h[3] + c * B0.w;
    h[4] = __expf(dt * Ar[4]) * h[4] + c * B1.x;
    h[5] = __expf(dt * Ar[5]) * h[5] + c * B1.y;
    h[6] = __expf(dt * Ar[6]) * h[6] + c * B1.z;
    h[7] = __expf(dt * Ar[7]) * h[7] + c * B1.w;
    float y01 = h[0] * C0.x + h[1] * C0.y;
    float y23 = h[2] * C0.z + h[3] * C0.w;
    float y45 = h[4] * C1.x + h[5] * C1.y;
    float y67 = h[6] * C1.z + h[7] * C1.w;
    float y = (y01 + y23) + (y45 + y67);
    y += __shfl_xor(y, 1, 4);
    y += __shfl_xor(y, 2, 4);
    if (q == 0) {
      const float z = (float)*pz;
      const float g = z / (1.0f + __expf(-z));
      *pyg = (__bf16)((y + x * dsk) * g);
    }
    px += DI;
    pR += 96;
    pz += 2 * DI;
    pyg += DI;
  }
}

// ---------------------------------------------------------------------------
extern "C" void kernel_launch(void* const* d_in, const int* in_sizes, int n_in,
                              void* d_out, int out_size, void* d_ws,
                              size_t ws_size, hipStream_t stream) {
  const float* x = (const float*)d_in[0];
  const float* in_w = (const float*)d_in[1];
  const float* conv_w = (const float*)d_in[2];
  const float* conv_b = (const float*)d_in[3];
  const float* xp_w = (const float*)d_in[4];
  const float* dt_w = (const float*)d_in[5];
  const float* dt_b = (const float*)d_in[6];
  const float* A_log = (const float*)d_in[7];
  const float* Dsk = (const float*)d_in[8];
  const float* out_w = (const float*)d_in[9];
  const float* norm_w = (const float*)d_in[10];
  float* out = (float*)d_out;

  // ---- bf16 weight mirrors (fixed region at start of ws) ----
  const size_t N_INW = (size_t)NL * 2 * DI * DM;   // 8.4M
  const size_t N_XPW = (size_t)NL * 96 * DI;       // 786K
  const size_t N_OUW = (size_t)NL * DM * DI;       // 4.2M
  __bf16* inw_b = (__bf16*)d_ws;
  __bf16* xpw_b = inw_b + N_INW;
  __bf16* outw_b = xpw_b + N_XPW;
  const size_t WBF = N_INW + N_XPW + N_OUW;  // bf16 elems (even)
  float* fbase = (float*)d_ws + WBF / 2;

  // ---- activations (f32-equivalent units per row):
  // xzb(bf16,1024) + xcb(bf16,512) + xdbl(96) + xnb(bf16,256) +
  // ygb(bf16,512) = 2400. Scan state per batch: 2*NCH*DS*DI + NCH*DI.
  int nchunk = 1;
  for (;;) {
    const int nb_try = BB / nchunk;
    const size_t rows_try = (size_t)nb_try * LL;
    const size_t need =
        (WBF / 2 + rows_try * 2400 +
         (size_t)nb_try * (2 * NCH * DS * DI + NCH * DI)) *
        sizeof(float);
    if (need <= ws_size || nchunk == 8) break;
    nchunk <<= 1;
  }
  const int nb = BB / nchunk;  // batches per chunk
  const int rows = nb * LL;    // rows per chunk

  __bf16* xzb = (__bf16*)fbase;                        // rows*2048 bf16
  __bf16* xcb = xzb + (size_t)rows * 2048;             // rows*1024 bf16
  float* xdbl = (float*)(xcb + (size_t)rows * 1024);   // rows*96 f32
  __bf16* xnb = (__bf16*)(xdbl + (size_t)rows * 96);   // rows*512 bf16
  __bf16* ygb = xnb + (size_t)rows * 512;              // rows*1024 bf16
  float* hend = (float*)(ygb + (size_t)rows * 1024);   // nb*NCH*DS*DI
  float* h_in = hend + (size_t)nb * NCH * DS * DI;     // nb*NCH*DS*DI
  float* Sdt = h_in + (size_t)nb * NCH * DS * DI;      // nb*NCH*DI

  // residual stream lives in d_out
  hipMemcpyAsync(out, x, (size_t)NROWS * DM * sizeof(float),
                 hipMemcpyDeviceToDevice, stream);

  // weight conversion (once per launch)
  f2b_kernel<<<4096, 256, 0, stream>>>(in_w, inw_b, (int)(N_INW / 4));
  f2b_kernel<<<768, 256, 0, stream>>>(xp_w, xpw_b, (int)(N_XPW / 4));
  f2b_kernel<<<2048, 256, 0, stream>>>(out_w, outw_b, (int)(N_OUW / 4));

  for (int layer = 0; layer < NL; ++layer) {
    const __bf16* l_inw = inw_b + (size_t)layer * 2 * DI * DM;
    const float* l_cw = conv_w + (size_t)layer * DI * 4;
    const float* l_cb = conv_b + (size_t)layer * DI;
    const __bf16* l_xpw = xpw_b + (size_t)layer * 96 * DI;
    const float* l_dtw = dt_w + (size_t)layer * DI * DR;
    const float* l_dtb = dt_b + (size_t)layer * DI;
    const float* l_al = A_log + (size_t)layer * DI * DS;
    const float* l_dsk = Dsk + (size_t)layer * DI;
    const __bf16* l_ow = outw_b + (size_t)layer * DM * DI;
    const float* l_nw = norm_w + (size_t)layer * DM;

    for (int c = 0; c < nchunk; ++c) {
      float* res = out + (size_t)c * rows * DM;

      rmsnorm_kernel<<<rows, 256, 0, stream>>>(res, l_nw, xnb);

      // in_proj: [rows,512] x [2048,512]^T -> bf16 [rows,2048]
      gemm_bf16<64, 4><<<dim3(16, rows / 128), 256, 0, stream>>>(
          xnb, DM, l_inw, DM, nullptr, 2 * DI, 2 * DI, DM, xzb);

      conv_silu_kernel<<<(rows * DI / 8) / 256, 256, 0, stream>>>(
          xzb, l_cw, l_cb, xcb);

      // x_proj: [rows,1024] x [96,1024]^T -> fp32 xdbl [rows,96]
      gemm_bf16<64, 0><<<dim3(1, rows / 128), 256, 0, stream>>>(
          xcb, DI, l_xpw, DI, xdbl, 96, 96, DI, nullptr);

      // chunk-parallel selective scan (dt_proj fused) -> bf16 gated y
      scan_phase1<<<nb * NCH * 16, 256, 0, stream>>>(xcb, xdbl, l_al, l_dtw,
                                                     l_dtb, hend, Sdt);
      scan_combine<<<nb * 128, 256, 0, stream>>>(l_al, Sdt, hend, h_in);
      scan_phase3<<<nb * NCH * 16, 256, 0, stream>>>(
          xcb, xdbl, xzb, l_al, l_dtw, l_dtb, l_dsk, h_in, ygb);

      // out_proj + residual: res += [rows,1024] x [512,1024]^T
      gemm_bf16<64, 2><<<dim3(4, rows / 128), 256, 0, stream>>>(
          ygb, DI, l_ow, DI, res, DM, DM, DI, nullptr);
    }
  }
}